// Round 12
// baseline (2676.636 us; speedup 1.0000x reference)
//
#include <hip/hip_runtime.h>
#include <hip/hip_fp16.h>
#include <hip/hip_fp8.h>
#include <stdint.h>

// Problem constants (NamedEntityRecognitionModel)
#define TAGS  32
#define EMB   256
#define HID   512
#define HSZ   256        // per-direction hidden
#define G4H   1024       // 4*HSZ
#define BATCH 64
#define TLEN  512

typedef _Float16 half8  __attribute__((ext_vector_type(8)));
typedef _Float16 half2v __attribute__((ext_vector_type(2)));
typedef float    f32x4  __attribute__((ext_vector_type(4)));
typedef unsigned int u32x2 __attribute__((ext_vector_type(2)));

#if defined(__has_builtin)
#if __has_builtin(__builtin_amdgcn_fdot2)
#define HAVE_FDOT2 1
#endif
#if __has_builtin(__builtin_amdgcn_cvt_pk_fp8_f32)
#define HAVE_CVTFP8 1
#endif
#endif

__device__ __forceinline__ float fdot2f(unsigned a, unsigned b, float c) {
    half2v ha = __builtin_bit_cast(half2v, a);
    half2v hb = __builtin_bit_cast(half2v, b);
#ifdef HAVE_FDOT2
    return __builtin_amdgcn_fdot2(ha, hb, c, false);
#else
    return c + (float)ha[0]*(float)hb[0] + (float)ha[1]*(float)hb[1];
#endif
}
__device__ __forceinline__ float sigmoid_f(float x){ return 1.0f/(1.0f+__expf(-x)); }
__device__ __forceinline__ float tanh_f(float x){ return 1.0f - 2.0f/(__expf(2.0f*x)+1.0f); }

// float -> OCP e4m3fn byte (HW convert when available)
__device__ __forceinline__ unsigned char to_fp8(float x) {
#ifdef HAVE_CVTFP8
    return (unsigned char)(__builtin_amdgcn_cvt_pk_fp8_f32(x, x, 0, false) & 0xff);
#else
    __hip_fp8_e4m3 q(x);
    return (unsigned char)q.__x;
#endif
}

// ---------------------------------------------------------------------------
// K0a: fp8 MFMA B-fragment image of Wh, scaled by 8.
// Slot: [dir][w 8][gg 8][ks 8][lane 64] x 8 bytes:
//   n = (gg>>1)*256 + w*32 + (gg&1)*16 + (lane&15), k = ks*32 + (lane>>4)*8 + e
// ---------------------------------------------------------------------------
__global__ __launch_bounds__(256)
void whimg_kernel(const float* __restrict__ WhF, const float* __restrict__ WhB,
                  unsigned long long* __restrict__ WhT8) {
    const int slot = blockIdx.x * 256 + threadIdx.x;   // 0..65535
    const int dir = slot >> 15, r = slot & 32767;
    const int lane = r & 63;
    const int ks = (r >> 6) & 7;
    const int gg = (r >> 9) & 7;
    const int w  = (r >> 12) & 7;
    const int n = (gg >> 1) * 256 + w * 32 + (gg & 1) * 16 + (lane & 15);
    const int k = ks * 32 + (lane >> 4) * 8;
    const float* src = (dir ? WhB : WhF) + (size_t)n * HSZ + k;
    unsigned long long v = 0;
#pragma unroll
    for (int e = 0; e < 8; ++e)
        v |= (unsigned long long)to_fp8(8.0f * src[e]) << (8 * e);
    WhT8[slot] = v;
}

// ---------------------------------------------------------------------------
// K0b: f16 MFMA B-fragment image of Wi (unscaled).
// ---------------------------------------------------------------------------
__global__ __launch_bounds__(256)
void wiimg_kernel(const float* __restrict__ WiF, const float* __restrict__ WiB,
                  half8* __restrict__ WiT) {
    const int slot = blockIdx.x * 256 + threadIdx.x;   // 0..65535
    const int lane = slot & 63;
    const int ks = (slot >> 6) & 7;
    const int nt = (slot >> 9) & 63;
    const int dir = slot >> 15;
    const int n = nt * 16 + (lane & 15);
    const int k = ks * 32 + (lane >> 4) * 8;
    const float* src = (dir ? WiB : WiF) + (size_t)n * EMB + k;
    half8 hv;
#pragma unroll
    for (int e = 0; e < 8; ++e) hv[e] = (_Float16)src[e];
    WiT[slot] = hv;
}

// ---------------------------------------------------------------------------
// K1: MFMA input GEMM. xWT[dir][bg][t][n 1024][16 b] = 64*(embed[X[b][t]].Wi[n] + bias[n])
// grid (512 t, 2 dir), block 256 (4 waves).
// ---------------------------------------------------------------------------
__global__ __launch_bounds__(256, 2)
void gemm_xwt_kernel(const int* __restrict__ X, const float* __restrict__ embed,
                     const half8* __restrict__ WiT, const float* __restrict__ bF,
                     const float* __restrict__ bB, __half* __restrict__ xWT) {
    const int t   = blockIdx.x;
    const int dir = blockIdx.y;
    const int tid = threadIdx.x;
    const int lane = tid & 63;
    const int w    = tid >> 6;
    const int l15  = lane & 15;
    const int lp   = lane >> 4;
    const float* bias = dir ? bB : bF;

    __shared__ ushort A[4 * 8 * 64 * 8];   // [mt][ks][lane][8e] f16 = 32 KB

    {
        const int b = tid >> 2, part = tid & 3;
        const int erow = X[b * TLEN + t];
        const float* src = embed + (size_t)erow * EMB + part * 64;
        const int mt = b >> 4, bl = b & 15;
#pragma unroll
        for (int q = 0; q < 2; ++q) {
            const int ks = part * 2 + q;
#pragma unroll
            for (int lpp = 0; lpp < 4; ++lpp) {
                const float4 x0 = *(const float4*)(src + q * 32 + lpp * 8);
                const float4 x1 = *(const float4*)(src + q * 32 + lpp * 8 + 4);
                half8 hv;
                hv[0]=(_Float16)x0.x; hv[1]=(_Float16)x0.y; hv[2]=(_Float16)x0.z; hv[3]=(_Float16)x0.w;
                hv[4]=(_Float16)x1.x; hv[5]=(_Float16)x1.y; hv[6]=(_Float16)x1.z; hv[7]=(_Float16)x1.w;
                *(half8*)&A[(((mt * 8 + ks) * 64) + lpp * 16 + bl) * 8] = hv;
            }
        }
    }
    __syncthreads();

    half8 afr[4][8];
#pragma unroll
    for (int mt = 0; mt < 4; ++mt)
#pragma unroll
        for (int ks = 0; ks < 8; ++ks)
            afr[mt][ks] = *(const half8*)&A[(((mt * 8 + ks) * 64) + lane) * 8];

    const half8* Bw = WiT + (size_t)(dir * 64 + w * 16) * 8 * 64;

    half8 bcur[8], bnxt[8];
#pragma unroll
    for (int ks = 0; ks < 8; ++ks) bcur[ks] = Bw[(size_t)ks * 64 + lane];

#pragma unroll
    for (int j = 0; j < 16; ++j) {
        if (j < 15) {
#pragma unroll
            for (int ks = 0; ks < 8; ++ks)
                bnxt[ks] = Bw[((size_t)(j + 1) * 8 + ks) * 64 + lane];
        }
        f32x4 acc4[4] = {};
#pragma unroll
        for (int ks = 0; ks < 8; ++ks)
#pragma unroll
            for (int mt = 0; mt < 4; ++mt)
                acc4[mt] = __builtin_amdgcn_mfma_f32_16x16x32_f16(afr[mt][ks], bcur[ks], acc4[mt], 0, 0, 0);

        const int nt = w * 16 + j;
        const float bs = bias[nt * 16 + l15];
#pragma unroll
        for (int mt = 0; mt < 4; ++mt) {
            unsigned long long pk = 0;
#pragma unroll
            for (int rr = 0; rr < 4; ++rr) {
                const __half hh = __float2half(64.0f * (acc4[mt][rr] + bs));
                pk |= (unsigned long long)__half_as_ushort(hh) << (16 * rr);
            }
            __half* dst = xWT + ((size_t)((dir * 4 + mt) * TLEN + t)) * (G4H * 16)
                        + (size_t)(nt * 16 + l15) * 16 + lp * 4;
            *(unsigned long long*)dst = pk;
        }
#pragma unroll
        for (int ks = 0; ks < 8; ++ks) bcur[ks] = bnxt[ks];
    }
}

// ---------------------------------------------------------------------------
// K2: batch-split LSTM. Wh fp8 in hard-coded AGPRs a0..a127 (init-once).
// Deltas vs R11: (1) MFMA asm is NON-volatile -> scheduler can hoist the
// h8 ds_reads and issue MFMAs at throughput; (2) ONE barrier per step via
// double-buffered h8/hstage (read buf p, write buf p^1, barrier, flip).
// grid (4 bg, 2 dir), block 512 (8 waves -> 2/SIMD).
// ---------------------------------------------------------------------------

// write one Wh qword into a literal AGPR pair (clobbers reserve the regs)
#define WBF1(SLOT, A0, A1)                                                   \
    {                                                                        \
        unsigned long long v_ = base[(SLOT) * 64 + lane];                    \
        unsigned lo_ = (unsigned)v_, hi_ = (unsigned)(v_ >> 32);             \
        asm volatile("v_accvgpr_write_b32 a" A0 ", %0\n\t"                   \
                     "v_accvgpr_write_b32 a" A1 ", %1"                       \
                     :: "v"(lo_), "v"(hi_) : "a" A0, "a" A1);                \
    }

// one MFMA with B sourced from a literal AGPR pair — NON-volatile so the
// scheduler may reorder/interleave subject to data deps on acc/areg.
#define MFMA1(ACC, A0, A1)                                                   \
    asm("v_mfma_f32_16x16x32_fp8_fp8 %0, %1, a[" A0 ":" A1 "], %0"           \
        : "+v"(ACC) : "v"(areg))

__global__ __launch_bounds__(512, 2)
void lstm_kernel(const __half* __restrict__ xWT,
                 const unsigned long long* __restrict__ WhT8,
                 __half* __restrict__ hist) {
    const int bg  = blockIdx.x;       // 0..3
    const int dir = blockIdx.y;       // 0..1
    const int tid = threadIdx.x;
    const int lane = tid & 63;
    const int w    = tid >> 6;        // wave 0..7
    const int l15  = lane & 15;
    const int lp   = lane >> 4;

    __shared__ unsigned char h8[2 * 4096];   // fp8(8*h): [p][b][u] XOR-swz, 8 KB
    __shared__ ushort hstage[2 * 4096];      // f16 h:    [p][b][u] XOR-swz, 16 KB

    const __half* xwD = xWT + (size_t)(dir * 4 + bg) * ((size_t)TLEN * G4H * 16);
    __half* hD = hist + (size_t)(dir * BATCH + bg * 16) * TLEN * HSZ;

    // ---- load 64 Wh fp8 B-frags into a0..a127 (slot s -> a[2s:2s+1]) ----
    {
        const unsigned long long* base = WhT8 + (size_t)(dir * 8 + w) * 4096;
        WBF1( 0,  "0",  "1") WBF1( 1,  "2",  "3") WBF1( 2,  "4",  "5") WBF1( 3,  "6",  "7")
        WBF1( 4,  "8",  "9") WBF1( 5, "10", "11") WBF1( 6, "12", "13") WBF1( 7, "14", "15")
        WBF1( 8, "16", "17") WBF1( 9, "18", "19") WBF1(10, "20", "21") WBF1(11, "22", "23")
        WBF1(12, "24", "25") WBF1(13, "26", "27") WBF1(14, "28", "29") WBF1(15, "30", "31")
        WBF1(16, "32", "33") WBF1(17, "34", "35") WBF1(18, "36", "37") WBF1(19, "38", "39")
        WBF1(20, "40", "41") WBF1(21, "42", "43") WBF1(22, "44", "45") WBF1(23, "46", "47")
        WBF1(24, "48", "49") WBF1(25, "50", "51") WBF1(26, "52", "53") WBF1(27, "54", "55")
        WBF1(28, "56", "57") WBF1(29, "58", "59") WBF1(30, "60", "61") WBF1(31, "62", "63")
        WBF1(32, "64", "65") WBF1(33, "66", "67") WBF1(34, "68", "69") WBF1(35, "70", "71")
        WBF1(36, "72", "73") WBF1(37, "74", "75") WBF1(38, "76", "77") WBF1(39, "78", "79")
        WBF1(40, "80", "81") WBF1(41, "82", "83") WBF1(42, "84", "85") WBF1(43, "86", "87")
        WBF1(44, "88", "89") WBF1(45, "90", "91") WBF1(46, "92", "93") WBF1(47, "94", "95")
        WBF1(48, "96", "97") WBF1(49, "98", "99") WBF1(50, "100", "101") WBF1(51, "102", "103")
        WBF1(52, "104", "105") WBF1(53, "106", "107") WBF1(54, "108", "109") WBF1(55, "110", "111")
        WBF1(56, "112", "113") WBF1(57, "114", "115") WBF1(58, "116", "117") WBF1(59, "118", "119")
        WBF1(60, "120", "121") WBF1(61, "122", "123") WBF1(62, "124", "125") WBF1(63, "126", "127")
        asm volatile("s_nop 7\n\ts_nop 7" :::);   // accvgpr_write -> mfma hazard guard
    }

    for (int i = tid; i < 1024; i += 512) ((unsigned int*)h8)[i] = 0;   // zero buf 0

    float c[8];
#pragma unroll
    for (int i = 0; i < 8; ++i) c[i] = 0.0f;

    const int swzA = (l15 & 7) << 4;
    int xoff[8];
#pragma unroll
    for (int gg = 0; gg < 8; ++gg)
        xoff[gg] = ((gg >> 1) * 256 + w * 32 + (gg & 1) * 16 + l15) * 16 + lp * 4;

    f32x4 acc[8];
    u32x2 xwc[8], xwn[8];
    {
        const __half* p0 = xwD + (size_t)(dir ? (TLEN - 1) : 0) * (G4H * 16);
#pragma unroll
        for (int gg = 0; gg < 8; ++gg)
            xwc[gg] = *(const u32x2*)(p0 + xoff[gg]);
    }
    __syncthreads();   // h8 init + AGPR loads complete

    int p = 0;
    for (int ts = 0; ts < TLEN; ++ts) {
        const int t = dir ? (TLEN - 1 - ts) : ts;
        const unsigned char* h8r = h8 + p * 4096;         // read buffer
        const int pb = p ^ 1;                              // write buffer

        // acc <- 64*xW(t)
#pragma unroll
        for (int gg = 0; gg < 8; ++gg) {
            const half2v lo = __builtin_bit_cast(half2v, xwc[gg][0]);
            const half2v hi = __builtin_bit_cast(half2v, xwc[gg][1]);
            f32x4 a; a[0]=(float)lo[0]; a[1]=(float)lo[1]; a[2]=(float)hi[0]; a[3]=(float)hi[1];
            acc[gg] = a;
        }

        // recurrent matmul: h8[p] (LDS) x a0..a127 (AGPR) -> acc
#define KS_BLOCK(KS, P0,P1, P2,P3, P4,P5, P6,P7, P8,P9, P10,P11, P12,P13, P14,P15) \
        {                                                                          \
            const unsigned long long areg = *(const unsigned long long*)           \
                (h8r + ((l15 * 256 + (KS) * 32 + lp * 8) ^ swzA));                 \
            MFMA1(acc[0], P0, P1);   MFMA1(acc[1], P2, P3);                        \
            MFMA1(acc[2], P4, P5);   MFMA1(acc[3], P6, P7);                        \
            MFMA1(acc[4], P8, P9);   MFMA1(acc[5], P10, P11);                      \
            MFMA1(acc[6], P12, P13); MFMA1(acc[7], P14, P15);                      \
        }
        KS_BLOCK(0,  "0","1",  "16","17", "32","33", "48","49", "64","65", "80","81", "96","97",  "112","113")
        KS_BLOCK(1,  "2","3",  "18","19", "34","35", "50","51", "66","67", "82","83", "98","99",  "114","115")
        KS_BLOCK(2,  "4","5",  "20","21", "36","37", "52","53", "68","69", "84","85", "100","101","116","117")
        KS_BLOCK(3,  "6","7",  "22","23", "38","39", "54","55", "70","71", "86","87", "102","103","118","119")
        KS_BLOCK(4,  "8","9",  "24","25", "40","41", "56","57", "72","73", "88","89", "104","105","120","121")
        KS_BLOCK(5, "10","11", "26","27", "42","43", "58","59", "74","75", "90","91", "106","107","122","123")
        KS_BLOCK(6, "12","13", "28","29", "44","45", "60","61", "76","77", "92","93", "108","109","124","125")
        KS_BLOCK(7, "14","15", "30","31", "46","47", "62","63", "78","79", "94","95", "110","111","126","127")
#undef KS_BLOCK

        // prefetch next step's xW (latency hides under cell update)
        {
            const int tn = dir ? (t > 0 ? t - 1 : 0) : (t < TLEN - 1 ? t + 1 : t);
            const __half* pp = xwD + (size_t)tn * (G4H * 16);
#pragma unroll
            for (int gg = 0; gg < 8; ++gg)
                xwn[gg] = *(const u32x2*)(pp + xoff[gg]);
        }

        // cell update; write h(t) into buffer p^1 (no barrier needed before:
        // buffer p^1 is not read by anyone until after the barrier below)
#pragma unroll
        for (int ng = 0; ng < 2; ++ng) {
            const int u = w * 32 + ng * 16 + l15;
#pragma unroll
            for (int rr = 0; rr < 4; ++rr) {
                const float sc = 0.015625f;   // 1/64 descale
                const float ig = sigmoid_f(acc[    ng][rr] * sc);
                const float fg = sigmoid_f(acc[2 + ng][rr] * sc);
                const float gv = tanh_f   (acc[4 + ng][rr] * sc);
                const float og = sigmoid_f(acc[6 + ng][rr] * sc);
                float cc = c[ng * 4 + rr];
                cc = fg * cc + ig * gv;
                c[ng * 4 + rr] = cc;
                const float hv = og * tanh_f(cc);
                const int b = lp * 4 + rr;
                const int sw = (b & 7) << 4;
                *(ushort*)((char*)hstage + pb * 8192 + ((b * 512 + u * 2) ^ sw)) =
                    __half_as_ushort(__float2half(hv));
                h8[pb * 4096 + ((b * 256 + u) ^ sw)] = to_fp8(8.0f * hv);
            }
        }
        __syncthreads();   // single barrier: h(t) visible to all waves

        // spill h(t) f16 -> hist (reads buffer p^1, written by all waves)
        {
            const int bl = tid >> 5, us = tid & 31;
            const uint4 v = *(const uint4*)((const char*)hstage + pb * 8192 +
                              ((bl * 512 + us * 16) ^ ((bl & 7) << 4)));
            *(uint4*)(hD + ((size_t)bl * TLEN + t) * HSZ + us * 8) = v;
        }

#pragma unroll
        for (int gg = 0; gg < 8; ++gg) xwc[gg] = xwn[gg];
        p ^= 1;
    }
}
#undef WBF1
#undef MFMA1

// ---------------------------------------------------------------------------
// K3: emissions em[b][t][k] = hf(b,t,:).fcW[k,0:256] + hb(b,t,:).fcW[k,256:512]
// ---------------------------------------------------------------------------
__global__ __launch_bounds__(256)
void em_kernel(const __half* __restrict__ hist, const float* __restrict__ fcW,
               float* __restrict__ em) {
    const int b   = blockIdx.x >> 3;
    const int t0  = (blockIdx.x & 7) * 64;
    const int tid = threadIdx.x;

    __shared__ ushort hf[64][264];
    __shared__ ushort hb[64][264];
    __shared__ ushort fcs[32][520];

    for (int i = tid; i < 32 * 512; i += 256) {
        const int k = i >> 9, j = i & 511;
        fcs[k][j] = __half_as_ushort(__float2half(fcW[(size_t)k * HID + j]));
    }
    const __half* hfp = hist;
    const __half* hbp = hist + (size_t)BATCH * TLEN * HSZ;
    for (int i = tid; i < 64 * 32; i += 256) {
        const int row = i >> 5, seg = i & 31;
        const uint4 vf = *(const uint4*)(hfp + ((size_t)b * TLEN + t0 + row) * HSZ + seg*8);
        const uint4 vb = *(const uint4*)(hbp + ((size_t)b * TLEN + t0 + row) * HSZ + seg*8);
        *(uint4*)&hf[row][seg*8] = vf;
        *(uint4*)&hb[row][seg*8] = vb;
    }
    __syncthreads();

    const int tok = tid >> 2;     // 0..63
    const int kq  = tid & 3;      // k = kq*8 + kk
    float s[8] = {0,0,0,0,0,0,0,0};
    for (int j2 = 0; j2 < 128; ++j2) {
        const unsigned hfv = *(const unsigned*)&hf[tok][j2*2];
        const unsigned hbv = *(const unsigned*)&hb[tok][j2*2];
#pragma unroll
        for (int kk = 0; kk < 8; ++kk) {
            const int k = kq*8 + kk;
            s[kk] = fdot2f(hfv, *(const unsigned*)&fcs[k][j2*2], s[kk]);
            s[kk] = fdot2f(hbv, *(const unsigned*)&fcs[k][256 + j2*2], s[kk]);
        }
    }
    float* dst = em + ((size_t)b * TLEN + t0 + tok) * TAGS + kq*8;
#pragma unroll
    for (int kk = 0; kk < 8; ++kk) dst[kk] = s[kk];
}

// ---------------------------------------------------------------------------
// K4: CRF forward + gold score per batch row. grid 64, block 64.
// ---------------------------------------------------------------------------
__global__ void crf_kernel(const float* __restrict__ em, const float* __restrict__ fcb,
                           const float* __restrict__ trans, const float* __restrict__ startv,
                           const float* __restrict__ endv, const int* __restrict__ y,
                           float* __restrict__ partial) {
    const int b   = blockIdx.x;
    const int tid = threadIdx.x;

    __shared__ float alpha_s[TAGS];
    __shared__ float trans_s[TAGS][TAGS + 1];

    for (int i = tid; i < TAGS * TAGS; i += 64)
        trans_s[i >> 5][i & 31] = trans[i];

    const float* e = em + (size_t)b * TLEN * TAGS;

    if (tid < TAGS)
        alpha_s[tid] = startv[tid] + e[tid] + fcb[tid];
    __syncthreads();

    for (int t = 1; t < TLEN; ++t) {
        float anew = 0.0f;
        if (tid < TAGS) {
            float mx = -3.0e38f;
#pragma unroll
            for (int k2 = 0; k2 < TAGS; ++k2)
                mx = fmaxf(mx, alpha_s[k2] + trans_s[k2][tid]);
            float sm = 0.0f;
#pragma unroll
            for (int k2 = 0; k2 < TAGS; ++k2)
                sm += __expf(alpha_s[k2] + trans_s[k2][tid] - mx);
            anew = mx + __logf(sm) + e[t * TAGS + tid] + fcb[tid];
        }
        __syncthreads();
        if (tid < TAGS) alpha_s[tid] = anew;
        __syncthreads();
    }

    float v = (tid < TAGS) ? (alpha_s[tid] + endv[tid]) : -1.0e30f;
    float mx = v;
#pragma unroll
    for (int off = 32; off; off >>= 1) mx = fmaxf(mx, __shfl_xor(mx, off, 64));
    float ex = __expf(v - mx);
#pragma unroll
    for (int off = 32; off; off >>= 1) ex += __shfl_xor(ex, off, 64);
    const float logZ = mx + __logf(ex);

    const int* yb = y + (size_t)b * TLEN;
    float gsum = 0.0f;
    for (int t = tid; t < TLEN; t += 64) {
        const int yt = yb[t];
        gsum += e[t * TAGS + yt] + fcb[yt];
    }
    for (int t = tid; t < TLEN - 1; t += 64)
        gsum += trans[yb[t] * TAGS + yb[t + 1]];
#pragma unroll
    for (int off = 32; off; off >>= 1) gsum += __shfl_xor(gsum, off, 64);

    if (tid == 0) {
        const float num = startv[yb[0]] + gsum + endv[yb[TLEN - 1]];
        partial[b] = logZ - num;
    }
}

// ---------------------------------------------------------------------------
// K5: final mean
// ---------------------------------------------------------------------------
__global__ void reduce_kernel(const float* __restrict__ partial, float* __restrict__ out) {
    float v = partial[threadIdx.x];
#pragma unroll
    for (int off = 32; off; off >>= 1) v += __shfl_xor(v, off, 64);
    if (threadIdx.x == 0) out[0] = v * (1.0f / BATCH);
}

// ---------------------------------------------------------------------------
extern "C" void kernel_launch(void* const* d_in, const int* in_sizes, int n_in,
                              void* d_out, int out_size, void* d_ws, size_t ws_size,
                              hipStream_t stream) {
    (void)in_sizes; (void)n_in; (void)out_size; (void)ws_size;

    const int*   X      = (const int*)  d_in[0];
    const int*   y      = (const int*)  d_in[1];
    const float* embed  = (const float*)d_in[2];
    const float* Wi_f   = (const float*)d_in[3];
    const float* Wh_f   = (const float*)d_in[4];
    const float* b_f    = (const float*)d_in[5];
    const float* Wi_b   = (const float*)d_in[6];
    const float* Wh_b   = (const float*)d_in[7];
    const float* b_b    = (const float*)d_in[8];
    const float* fcW    = (const float*)d_in[9];
    const float* fcb    = (const float*)d_in[10];
    const float* trans  = (const float*)d_in[11];
    const float* startv = (const float*)d_in[12];
    const float* endv   = (const float*)d_in[13];
    float* out = (float*)d_out;

    // workspace layout (em aliases xWT: xWT is dead once lstm_kernel finishes)
    char* ws = (char*)d_ws;
    __half* xWT  = (__half*)(ws);                        // [2][4][512][1024][16] f16 = 134217728 B
    float*  em   = (float*) (ws);                        // alias: [64][512][32] f32 = 4194304 B
    __half* hist = (__half*)(ws + 134217728);            // [2][64][512][256] f16 = 33554432 B
    unsigned long long* WhT8 = (unsigned long long*)(ws + 167772160);  // fp8 Wh image, 524288 B
    half8*  WiT  = (half8*) (ws + 168296448);            // f16 Wi image, 1048576 B
    float*  prt  = (float*) (ws + 169345024);            // 256 B

    whimg_kernel<<<256, 256, 0, stream>>>(Wh_f, Wh_b, WhT8);
    wiimg_kernel<<<256, 256, 0, stream>>>(Wi_f, Wi_b, WiT);

    dim3 ggrid(TLEN, 2);
    gemm_xwt_kernel<<<ggrid, 256, 0, stream>>>(X, embed, WiT, b_f, b_b, xWT);

    dim3 lgrid(4, 2);
    lstm_kernel<<<lgrid, 512, 0, stream>>>(xWT, WhT8, hist);

    em_kernel<<<BATCH * 8, 256, 0, stream>>>(hist, fcW, em);

    crf_kernel<<<BATCH, 64, 0, stream>>>(em, fcb, trans, startv, endv, y, prt);

    reduce_kernel<<<1, 64, 0, stream>>>(prt, out);
}

// Round 13
// 1616.982 us; speedup vs baseline: 1.6553x; 1.6553x over previous
//
#include <hip/hip_runtime.h>
#include <hip/hip_fp16.h>
#include <hip/hip_fp8.h>
#include <stdint.h>

// Problem constants (NamedEntityRecognitionModel)
#define TAGS  32
#define EMB   256
#define HID   512
#define HSZ   256        // per-direction hidden
#define G4H   1024       // 4*HSZ
#define BATCH 64
#define TLEN  512

typedef _Float16 half8  __attribute__((ext_vector_type(8)));
typedef _Float16 half2v __attribute__((ext_vector_type(2)));
typedef float    f32x4  __attribute__((ext_vector_type(4)));
typedef unsigned int u32x2 __attribute__((ext_vector_type(2)));

#if defined(__has_builtin)
#if __has_builtin(__builtin_amdgcn_fdot2)
#define HAVE_FDOT2 1
#endif
#if __has_builtin(__builtin_amdgcn_cvt_pk_fp8_f32)
#define HAVE_CVTFP8 1
#endif
#endif

__device__ __forceinline__ float fdot2f(unsigned a, unsigned b, float c) {
    half2v ha = __builtin_bit_cast(half2v, a);
    half2v hb = __builtin_bit_cast(half2v, b);
#ifdef HAVE_FDOT2
    return __builtin_amdgcn_fdot2(ha, hb, c, false);
#else
    return c + (float)ha[0]*(float)hb[0] + (float)ha[1]*(float)hb[1];
#endif
}
__device__ __forceinline__ float sigmoid_f(float x){ return 1.0f/(1.0f+__expf(-x)); }
__device__ __forceinline__ float tanh_f(float x){ return 1.0f - 2.0f/(__expf(2.0f*x)+1.0f); }

// float -> OCP e4m3fn byte (HW convert when available)
__device__ __forceinline__ unsigned char to_fp8(float x) {
#ifdef HAVE_CVTFP8
    return (unsigned char)(__builtin_amdgcn_cvt_pk_fp8_f32(x, x, 0, false) & 0xff);
#else
    __hip_fp8_e4m3 q(x);
    return (unsigned char)q.__x;
#endif
}

// ---------------------------------------------------------------------------
// K0a: fp8 MFMA B-fragment image of Wh, scaled by 8.
// Slot: [dir][w 8][gg 8][ks 8][lane 64] x 8 bytes:
//   n = (gg>>1)*256 + w*32 + (gg&1)*16 + (lane&15), k = ks*32 + (lane>>4)*8 + e
// ---------------------------------------------------------------------------
__global__ __launch_bounds__(256)
void whimg_kernel(const float* __restrict__ WhF, const float* __restrict__ WhB,
                  unsigned long long* __restrict__ WhT8) {
    const int slot = blockIdx.x * 256 + threadIdx.x;   // 0..65535
    const int dir = slot >> 15, r = slot & 32767;
    const int lane = r & 63;
    const int ks = (r >> 6) & 7;
    const int gg = (r >> 9) & 7;
    const int w  = (r >> 12) & 7;
    const int n = (gg >> 1) * 256 + w * 32 + (gg & 1) * 16 + (lane & 15);
    const int k = ks * 32 + (lane >> 4) * 8;
    const float* src = (dir ? WhB : WhF) + (size_t)n * HSZ + k;
    unsigned long long v = 0;
#pragma unroll
    for (int e = 0; e < 8; ++e)
        v |= (unsigned long long)to_fp8(8.0f * src[e]) << (8 * e);
    WhT8[slot] = v;
}

// ---------------------------------------------------------------------------
// K0b: f16 MFMA B-fragment image of Wi (unscaled).
// ---------------------------------------------------------------------------
__global__ __launch_bounds__(256)
void wiimg_kernel(const float* __restrict__ WiF, const float* __restrict__ WiB,
                  half8* __restrict__ WiT) {
    const int slot = blockIdx.x * 256 + threadIdx.x;   // 0..65535
    const int lane = slot & 63;
    const int ks = (slot >> 6) & 7;
    const int nt = (slot >> 9) & 63;
    const int dir = slot >> 15;
    const int n = nt * 16 + (lane & 15);
    const int k = ks * 32 + (lane >> 4) * 8;
    const float* src = (dir ? WiB : WiF) + (size_t)n * EMB + k;
    half8 hv;
#pragma unroll
    for (int e = 0; e < 8; ++e) hv[e] = (_Float16)src[e];
    WiT[slot] = hv;
}

// ---------------------------------------------------------------------------
// K1: MFMA input GEMM. xWT[dir][bg 16][t][n 1024][4 b] = 64*(embed.Wi + bias)
// grid (512 t, 2 dir), block 256 (4 waves).
// ---------------------------------------------------------------------------
__global__ __launch_bounds__(256, 2)
void gemm_xwt_kernel(const int* __restrict__ X, const float* __restrict__ embed,
                     const half8* __restrict__ WiT, const float* __restrict__ bF,
                     const float* __restrict__ bB, __half* __restrict__ xWT) {
    const int t   = blockIdx.x;
    const int dir = blockIdx.y;
    const int tid = threadIdx.x;
    const int lane = tid & 63;
    const int w    = tid >> 6;
    const int l15  = lane & 15;
    const int lp   = lane >> 4;
    const float* bias = dir ? bB : bF;

    __shared__ ushort A[4 * 8 * 64 * 8];   // [mt][ks][lane][8e] f16 = 32 KB
    __shared__ ushort tr[64][72];          // [n_local][b 64] staging

    {
        const int b = tid >> 2, part = tid & 3;
        const int erow = X[b * TLEN + t];
        const float* src = embed + (size_t)erow * EMB + part * 64;
        const int mt = b >> 4, bl = b & 15;
#pragma unroll
        for (int q = 0; q < 2; ++q) {
            const int ks = part * 2 + q;
#pragma unroll
            for (int lpp = 0; lpp < 4; ++lpp) {
                const float4 x0 = *(const float4*)(src + q * 32 + lpp * 8);
                const float4 x1 = *(const float4*)(src + q * 32 + lpp * 8 + 4);
                half8 hv;
                hv[0]=(_Float16)x0.x; hv[1]=(_Float16)x0.y; hv[2]=(_Float16)x0.z; hv[3]=(_Float16)x0.w;
                hv[4]=(_Float16)x1.x; hv[5]=(_Float16)x1.y; hv[6]=(_Float16)x1.z; hv[7]=(_Float16)x1.w;
                *(half8*)&A[(((mt * 8 + ks) * 64) + lpp * 16 + bl) * 8] = hv;
            }
        }
    }
    __syncthreads();

    half8 afr[4][8];
#pragma unroll
    for (int mt = 0; mt < 4; ++mt)
#pragma unroll
        for (int ks = 0; ks < 8; ++ks)
            afr[mt][ks] = *(const half8*)&A[(((mt * 8 + ks) * 64) + lane) * 8];

    const half8* Bw = WiT + (size_t)(dir * 64 + w * 16) * 8 * 64;

    half8 bcur[8], bnxt[8];
#pragma unroll
    for (int ks = 0; ks < 8; ++ks) bcur[ks] = Bw[(size_t)ks * 64 + lane];

    // process 4 n-tiles per wave per "jj" chunk; stage results in tr then
    // write in the new 4-batch-group layout at the end of each chunk group.
#pragma unroll
    for (int j = 0; j < 16; ++j) {
        if (j < 15) {
#pragma unroll
            for (int ks = 0; ks < 8; ++ks)
                bnxt[ks] = Bw[((size_t)(j + 1) * 8 + ks) * 64 + lane];
        }
        f32x4 acc4[4] = {};
#pragma unroll
        for (int ks = 0; ks < 8; ++ks)
#pragma unroll
            for (int mt = 0; mt < 4; ++mt)
                acc4[mt] = __builtin_amdgcn_mfma_f32_16x16x32_f16(afr[mt][ks], bcur[ks], acc4[mt], 0, 0, 0);

        const int nt = w * 16 + j;
        const float bs = bias[nt * 16 + l15];
        // write directly: rows = batch (mt*16 + lp*4 + rr), col n = nt*16+l15
#pragma unroll
        for (int mt = 0; mt < 4; ++mt) {
#pragma unroll
            for (int rr = 0; rr < 4; ++rr) {
                const int b = mt * 16 + lp * 4 + rr;
                const __half hh = __float2half(64.0f * (acc4[mt][rr] + bs));
                const int bgD = b >> 2, bo = b & 3;
                xWT[((size_t)((dir * 16 + bgD) * TLEN + t)) * (G4H * 4)
                    + (size_t)(nt * 16 + l15) * 4 + bo] = hh;
            }
        }
#pragma unroll
        for (int ks = 0; ks < 8; ++ks) bcur[ks] = bnxt[ks];
    }
    (void)tr;
}

// ---------------------------------------------------------------------------
// K2: batch-split LSTM v3 — 4 batches/block, 32 blocks (16 bg x 2 dir).
// Wh fp8 in hard-coded AGPRs a0..a127. Cell update REDISTRIBUTED via LDS
// gbuf so all 64 lanes are full during the transcendental-heavy phase
// (R12 counters: per-CU issue port 91% saturated, trans-dominated).
// block 512 (8 waves -> 2/SIMD). 2 barriers/step.
// ---------------------------------------------------------------------------

#define WBF1(SLOT, A0, A1)                                                   \
    {                                                                        \
        unsigned long long v_ = base[(SLOT) * 64 + lane];                    \
        unsigned lo_ = (unsigned)v_, hi_ = (unsigned)(v_ >> 32);             \
        asm volatile("v_accvgpr_write_b32 a" A0 ", %0\n\t"                   \
                     "v_accvgpr_write_b32 a" A1 ", %1"                       \
                     :: "v"(lo_), "v"(hi_) : "a" A0, "a" A1);                \
    }

#define MFMA1(ACC, A0, A1)                                                   \
    asm("v_mfma_f32_16x16x32_fp8_fp8 %0, %1, a[" A0 ":" A1 "], %0"           \
        : "+v"(ACC) : "v"(areg))

__global__ __launch_bounds__(512, 2)
void lstm_kernel(const __half* __restrict__ xWT,
                 const unsigned long long* __restrict__ WhT8,
                 __half* __restrict__ hist) {
    const int bg  = blockIdx.x;       // 0..15 (4 batches each)
    const int dir = blockIdx.y;       // 0..1
    const int tid = threadIdx.x;
    const int lane = tid & 63;
    const int w    = tid >> 6;        // wave 0..7
    const int l15  = lane & 15;
    const int lp   = lane >> 4;

    __shared__ unsigned char h8[4096];       // fp8(8*h): [b16][u256] XOR-swz; rows 4..15 stay 0
    __shared__ float gbuf[4 * 4 * 256];      // [b4][gate4][u256] f32 = 16 KB
    __shared__ ushort hstage[4 * 256];       // f16 h: [b4][u256] = 2 KB

    const __half* xwD = xWT + (size_t)(dir * 16 + bg) * ((size_t)TLEN * G4H * 4);
    __half* hD = hist + (size_t)(dir * BATCH + bg * 4) * TLEN * HSZ;

    // ---- load 64 Wh fp8 B-frags into a0..a127 (slot s -> a[2s:2s+1]) ----
    {
        const unsigned long long* base = WhT8 + (size_t)(dir * 8 + w) * 4096;
        WBF1( 0,  "0",  "1") WBF1( 1,  "2",  "3") WBF1( 2,  "4",  "5") WBF1( 3,  "6",  "7")
        WBF1( 4,  "8",  "9") WBF1( 5, "10", "11") WBF1( 6, "12", "13") WBF1( 7, "14", "15")
        WBF1( 8, "16", "17") WBF1( 9, "18", "19") WBF1(10, "20", "21") WBF1(11, "22", "23")
        WBF1(12, "24", "25") WBF1(13, "26", "27") WBF1(14, "28", "29") WBF1(15, "30", "31")
        WBF1(16, "32", "33") WBF1(17, "34", "35") WBF1(18, "36", "37") WBF1(19, "38", "39")
        WBF1(20, "40", "41") WBF1(21, "42", "43") WBF1(22, "44", "45") WBF1(23, "46", "47")
        WBF1(24, "48", "49") WBF1(25, "50", "51") WBF1(26, "52", "53") WBF1(27, "54", "55")
        WBF1(28, "56", "57") WBF1(29, "58", "59") WBF1(30, "60", "61") WBF1(31, "62", "63")
        WBF1(32, "64", "65") WBF1(33, "66", "67") WBF1(34, "68", "69") WBF1(35, "70", "71")
        WBF1(36, "72", "73") WBF1(37, "74", "75") WBF1(38, "76", "77") WBF1(39, "78", "79")
        WBF1(40, "80", "81") WBF1(41, "82", "83") WBF1(42, "84", "85") WBF1(43, "86", "87")
        WBF1(44, "88", "89") WBF1(45, "90", "91") WBF1(46, "92", "93") WBF1(47, "94", "95")
        WBF1(48, "96", "97") WBF1(49, "98", "99") WBF1(50, "100", "101") WBF1(51, "102", "103")
        WBF1(52, "104", "105") WBF1(53, "106", "107") WBF1(54, "108", "109") WBF1(55, "110", "111")
        WBF1(56, "112", "113") WBF1(57, "114", "115") WBF1(58, "116", "117") WBF1(59, "118", "119")
        WBF1(60, "120", "121") WBF1(61, "122", "123") WBF1(62, "124", "125") WBF1(63, "126", "127")
        asm volatile("s_nop 7\n\ts_nop 7" :::);
    }

    for (int i = tid; i < 1024; i += 512) ((unsigned int*)h8)[i] = 0;

    float c0 = 0.0f, c1 = 0.0f;   // cell state for (b=tid>>8, u=tid&255) and (b+2, u)

    const int swzA = (l15 & 7) << 4;
    int xoff[8];
#pragma unroll
    for (int gg = 0; gg < 8; ++gg)
        xoff[gg] = ((gg >> 1) * 256 + w * 32 + (gg & 1) * 16 + l15) * 4;

    f32x4 acc[8];
    u32x2 xwc[8], xwn[8];
    {
        const __half* p0 = xwD + (size_t)(dir ? (TLEN - 1) : 0) * (G4H * 4);
#pragma unroll
        for (int gg = 0; gg < 8; ++gg)
            xwc[gg] = *(const u32x2*)(p0 + xoff[gg]);
    }
    __syncthreads();   // h8 init + AGPR loads complete

    for (int ts = 0; ts < TLEN; ++ts) {
        const int t = dir ? (TLEN - 1 - ts) : ts;

        // acc <- 64*xW(t): u32x2 = 4 f16 for batches 0..3 (valid rows lp==0)
#pragma unroll
        for (int gg = 0; gg < 8; ++gg) {
            const half2v lo = __builtin_bit_cast(half2v, xwc[gg][0]);
            const half2v hi = __builtin_bit_cast(half2v, xwc[gg][1]);
            f32x4 a; a[0]=(float)lo[0]; a[1]=(float)lo[1]; a[2]=(float)hi[0]; a[3]=(float)hi[1];
            acc[gg] = a;
        }

        // recurrent matmul: h8 (LDS, rows 0-3 live) x a0..a127 (AGPR) -> acc
#define KS_BLOCK(KS, P0,P1, P2,P3, P4,P5, P6,P7, P8,P9, P10,P11, P12,P13, P14,P15) \
        {                                                                          \
            const unsigned long long areg = *(const unsigned long long*)           \
                (h8 + ((l15 * 256 + (KS) * 32 + lp * 8) ^ swzA));                  \
            MFMA1(acc[0], P0, P1);   MFMA1(acc[1], P2, P3);                        \
            MFMA1(acc[2], P4, P5);   MFMA1(acc[3], P6, P7);                        \
            MFMA1(acc[4], P8, P9);   MFMA1(acc[5], P10, P11);                      \
            MFMA1(acc[6], P12, P13); MFMA1(acc[7], P14, P15);                      \
        }
        KS_BLOCK(0,  "0","1",  "16","17", "32","33", "48","49", "64","65", "80","81", "96","97",  "112","113")
        KS_BLOCK(1,  "2","3",  "18","19", "34","35", "50","51", "66","67", "82","83", "98","99",  "114","115")
        KS_BLOCK(2,  "4","5",  "20","21", "36","37", "52","53", "68","69", "84","85", "100","101","116","117")
        KS_BLOCK(3,  "6","7",  "22","23", "38","39", "54","55", "70","71", "86","87", "102","103","118","119")
        KS_BLOCK(4,  "8","9",  "24","25", "40","41", "56","57", "72","73", "88","89", "104","105","120","121")
        KS_BLOCK(5, "10","11", "26","27", "42","43", "58","59", "74","75", "90","91", "106","107","122","123")
        KS_BLOCK(6, "12","13", "28","29", "44","45", "60","61", "76","77", "92","93", "108","109","124","125")
        KS_BLOCK(7, "14","15", "30","31", "46","47", "62","63", "78","79", "94","95", "110","111","126","127")
#undef KS_BLOCK

        // prefetch next step's xW (latency hides under gbuf+update phases)
        {
            const int tn = dir ? (t > 0 ? t - 1 : 0) : (t < TLEN - 1 ? t + 1 : t);
            const __half* pp = xwD + (size_t)tn * (G4H * 4);
#pragma unroll
            for (int gg = 0; gg < 8; ++gg)
                xwn[gg] = *(const u32x2*)(pp + xoff[gg]);
        }

        // scatter valid gate values (rows 0-3 live in lp==0 lanes) to gbuf
        if (lp == 0) {
            const int ubase = w * 32 + l15;   // + (gg&1)*16
#pragma unroll
            for (int gg = 0; gg < 8; ++gg) {
                const int g = gg >> 1;
                const int u = ubase + (gg & 1) * 16;
#pragma unroll
                for (int rr = 0; rr < 4; ++rr)
                    gbuf[(rr * 4 + g) * 256 + u] = acc[gg][rr];
            }
        }
        __syncthreads();   // B1: gbuf ready

        // full-lane cell update: 1024 (b,u) pairs over 512 threads (2 each)
        {
            const int u = tid & 255, b0 = tid >> 8;   // b0 in {0,1}; also b0+2
            const float sc = 0.015625f;               // 1/64 descale
#pragma unroll
            for (int half = 0; half < 2; ++half) {
                const int b = b0 + half * 2;
                float& cc = half ? c1 : c0;
                const float gi = gbuf[(b * 4 + 0) * 256 + u];
                const float gf = gbuf[(b * 4 + 1) * 256 + u];
                const float gg_ = gbuf[(b * 4 + 2) * 256 + u];
                const float go = gbuf[(b * 4 + 3) * 256 + u];
                const float ig = sigmoid_f(gi * sc);
                const float fg = sigmoid_f(gf * sc);
                const float gv = tanh_f(gg_ * sc);
                const float og = sigmoid_f(go * sc);
                cc = fg * cc + ig * gv;
                const float hv = og * tanh_f(cc);
                const int sw = (b & 7) << 4;
                hstage[b * 256 + u] = __half_as_ushort(__float2half(hv));
                h8[(b * 256 + u) ^ sw] = to_fp8(8.0f * hv);
            }
        }
        __syncthreads();   // B2: h(t) complete

        // spill h(t) f16 -> hist (2 KB: 512 thr x 4 B)
        {
            const int bl = tid >> 7, us = tid & 127;
            const unsigned v = *(const unsigned*)&hstage[bl * 256 + us * 2];
            *(unsigned*)(hD + ((size_t)bl * TLEN + t) * HSZ + us * 2) = v;
        }

#pragma unroll
        for (int gg = 0; gg < 8; ++gg) xwc[gg] = xwn[gg];
    }
}
#undef WBF1
#undef MFMA1

// ---------------------------------------------------------------------------
// K3: emissions em[b][t][k] = hf(b,t,:).fcW[k,0:256] + hb(b,t,:).fcW[k,256:512]
// ---------------------------------------------------------------------------
__global__ __launch_bounds__(256)
void em_kernel(const __half* __restrict__ hist, const float* __restrict__ fcW,
               float* __restrict__ em) {
    const int b   = blockIdx.x >> 3;
    const int t0  = (blockIdx.x & 7) * 64;
    const int tid = threadIdx.x;

    __shared__ ushort hf[64][264];
    __shared__ ushort hb[64][264];
    __shared__ ushort fcs[32][520];

    for (int i = tid; i < 32 * 512; i += 256) {
        const int k = i >> 9, j = i & 511;
        fcs[k][j] = __half_as_ushort(__float2half(fcW[(size_t)k * HID + j]));
    }
    const __half* hfp = hist;
    const __half* hbp = hist + (size_t)BATCH * TLEN * HSZ;
    for (int i = tid; i < 64 * 32; i += 256) {
        const int row = i >> 5, seg = i & 31;
        const uint4 vf = *(const uint4*)(hfp + ((size_t)b * TLEN + t0 + row) * HSZ + seg*8);
        const uint4 vb = *(const uint4*)(hbp + ((size_t)b * TLEN + t0 + row) * HSZ + seg*8);
        *(uint4*)&hf[row][seg*8] = vf;
        *(uint4*)&hb[row][seg*8] = vb;
    }
    __syncthreads();

    const int tok = tid >> 2;     // 0..63
    const int kq  = tid & 3;      // k = kq*8 + kk
    float s[8] = {0,0,0,0,0,0,0,0};
    for (int j2 = 0; j2 < 128; ++j2) {
        const unsigned hfv = *(const unsigned*)&hf[tok][j2*2];
        const unsigned hbv = *(const unsigned*)&hb[tok][j2*2];
#pragma unroll
        for (int kk = 0; kk < 8; ++kk) {
            const int k = kq*8 + kk;
            s[kk] = fdot2f(hfv, *(const unsigned*)&fcs[k][j2*2], s[kk]);
            s[kk] = fdot2f(hbv, *(const unsigned*)&fcs[k][256 + j2*2], s[kk]);
        }
    }
    float* dst = em + ((size_t)b * TLEN + t0 + tok) * TAGS + kq*8;
#pragma unroll
    for (int kk = 0; kk < 8; ++kk) dst[kk] = s[kk];
}

// ---------------------------------------------------------------------------
// K4: CRF forward + gold score per batch row. grid 64, block 64.
// ---------------------------------------------------------------------------
__global__ void crf_kernel(const float* __restrict__ em, const float* __restrict__ fcb,
                           const float* __restrict__ trans, const float* __restrict__ startv,
                           const float* __restrict__ endv, const int* __restrict__ y,
                           float* __restrict__ partial) {
    const int b   = blockIdx.x;
    const int tid = threadIdx.x;

    __shared__ float alpha_s[TAGS];
    __shared__ float trans_s[TAGS][TAGS + 1];

    for (int i = tid; i < TAGS * TAGS; i += 64)
        trans_s[i >> 5][i & 31] = trans[i];

    const float* e = em + (size_t)b * TLEN * TAGS;

    if (tid < TAGS)
        alpha_s[tid] = startv[tid] + e[tid] + fcb[tid];
    __syncthreads();

    for (int t = 1; t < TLEN; ++t) {
        float anew = 0.0f;
        if (tid < TAGS) {
            float mx = -3.0e38f;
#pragma unroll
            for (int k2 = 0; k2 < TAGS; ++k2)
                mx = fmaxf(mx, alpha_s[k2] + trans_s[k2][tid]);
            float sm = 0.0f;
#pragma unroll
            for (int k2 = 0; k2 < TAGS; ++k2)
                sm += __expf(alpha_s[k2] + trans_s[k2][tid] - mx);
            anew = mx + __logf(sm) + e[t * TAGS + tid] + fcb[tid];
        }
        __syncthreads();
        if (tid < TAGS) alpha_s[tid] = anew;
        __syncthreads();
    }

    float v = (tid < TAGS) ? (alpha_s[tid] + endv[tid]) : -1.0e30f;
    float mx = v;
#pragma unroll
    for (int off = 32; off; off >>= 1) mx = fmaxf(mx, __shfl_xor(mx, off, 64));
    float ex = __expf(v - mx);
#pragma unroll
    for (int off = 32; off; off >>= 1) ex += __shfl_xor(ex, off, 64);
    const float logZ = mx + __logf(ex);

    const int* yb = y + (size_t)b * TLEN;
    float gsum = 0.0f;
    for (int t = tid; t < TLEN; t += 64) {
        const int yt = yb[t];
        gsum += e[t * TAGS + yt] + fcb[yt];
    }
    for (int t = tid; t < TLEN - 1; t += 64)
        gsum += trans[yb[t] * TAGS + yb[t + 1]];
#pragma unroll
    for (int off = 32; off; off >>= 1) gsum += __shfl_xor(gsum, off, 64);

    if (tid == 0) {
        const float num = startv[yb[0]] + gsum + endv[yb[TLEN - 1]];
        partial[b] = logZ - num;
    }
}

// ---------------------------------------------------------------------------
// K5: final mean
// ---------------------------------------------------------------------------
__global__ void reduce_kernel(const float* __restrict__ partial, float* __restrict__ out) {
    float v = partial[threadIdx.x];
#pragma unroll
    for (int off = 32; off; off >>= 1) v += __shfl_xor(v, off, 64);
    if (threadIdx.x == 0) out[0] = v * (1.0f / BATCH);
}

// ---------------------------------------------------------------------------
extern "C" void kernel_launch(void* const* d_in, const int* in_sizes, int n_in,
                              void* d_out, int out_size, void* d_ws, size_t ws_size,
                              hipStream_t stream) {
    (void)in_sizes; (void)n_in; (void)out_size; (void)ws_size;

    const int*   X      = (const int*)  d_in[0];
    const int*   y      = (const int*)  d_in[1];
    const float* embed  = (const float*)d_in[2];
    const float* Wi_f   = (const float*)d_in[3];
    const float* Wh_f   = (const float*)d_in[4];
    const float* b_f    = (const float*)d_in[5];
    const float* Wi_b   = (const float*)d_in[6];
    const float* Wh_b   = (const float*)d_in[7];
    const float* b_b    = (const float*)d_in[8];
    const float* fcW    = (const float*)d_in[9];
    const float* fcb    = (const float*)d_in[10];
    const float* trans  = (const float*)d_in[11];
    const float* startv = (const float*)d_in[12];
    const float* endv   = (const float*)d_in[13];
    float* out = (float*)d_out;

    // workspace layout (em aliases xWT: xWT is dead once lstm_kernel finishes)
    char* ws = (char*)d_ws;
    __half* xWT  = (__half*)(ws);                        // [2][16][512][1024][4] f16 = 134217728 B
    float*  em   = (float*) (ws);                        // alias: [64][512][32] f32 = 4194304 B
    __half* hist = (__half*)(ws + 134217728);            // [2][64][512][256] f16 = 33554432 B
    unsigned long long* WhT8 = (unsigned long long*)(ws + 167772160);  // fp8 Wh image, 524288 B
    half8*  WiT  = (half8*) (ws + 168296448);            // f16 Wi image, 1048576 B
    float*  prt  = (float*) (ws + 169345024);            // 256 B

    whimg_kernel<<<256, 256, 0, stream>>>(Wh_f, Wh_b, WhT8);
    wiimg_kernel<<<256, 256, 0, stream>>>(Wi_f, Wi_b, WiT);

    dim3 ggrid(TLEN, 2);
    gemm_xwt_kernel<<<ggrid, 256, 0, stream>>>(X, embed, WiT, b_f, b_b, xWT);

    dim3 lgrid(16, 2);
    lstm_kernel<<<lgrid, 512, 0, stream>>>(xWT, WhT8, hist);

    em_kernel<<<BATCH * 8, 256, 0, stream>>>(hist, fcW, em);

    crf_kernel<<<BATCH, 64, 0, stream>>>(em, fcb, trans, startv, endv, y, prt);

    reduce_kernel<<<1, 64, 0, stream>>>(prt, out);
}

// Round 14
// 1610.903 us; speedup vs baseline: 1.6616x; 1.0038x over previous
//
#include <hip/hip_runtime.h>
#include <hip/hip_fp16.h>
#include <hip/hip_fp8.h>
#include <stdint.h>

// Problem constants (NamedEntityRecognitionModel)
#define TAGS  32
#define EMB   256
#define HID   512
#define HSZ   256        // per-direction hidden
#define G4H   1024       // 4*HSZ
#define BATCH 64
#define TLEN  512

typedef _Float16 half8  __attribute__((ext_vector_type(8)));
typedef _Float16 half2v __attribute__((ext_vector_type(2)));
typedef float    f32x4  __attribute__((ext_vector_type(4)));
typedef unsigned int u32x2 __attribute__((ext_vector_type(2)));

#if defined(__has_builtin)
#if __has_builtin(__builtin_amdgcn_fdot2)
#define HAVE_FDOT2 1
#endif
#if __has_builtin(__builtin_amdgcn_cvt_pk_fp8_f32)
#define HAVE_CVTFP8 1
#endif
#endif

__device__ __forceinline__ float fdot2f(unsigned a, unsigned b, float c) {
    half2v ha = __builtin_bit_cast(half2v, a);
    half2v hb = __builtin_bit_cast(half2v, b);
#ifdef HAVE_FDOT2
    return __builtin_amdgcn_fdot2(ha, hb, c, false);
#else
    return c + (float)ha[0]*(float)hb[0] + (float)ha[1]*(float)hb[1];
#endif
}
__device__ __forceinline__ float sigmoid_f(float x){ return 1.0f/(1.0f+__expf(-x)); }
__device__ __forceinline__ float tanh_f(float x){ return 1.0f - 2.0f/(__expf(2.0f*x)+1.0f); }

// float -> OCP e4m3fn byte (HW convert when available)
__device__ __forceinline__ unsigned char to_fp8(float x) {
#ifdef HAVE_CVTFP8
    return (unsigned char)(__builtin_amdgcn_cvt_pk_fp8_f32(x, x, 0, false) & 0xff);
#else
    __hip_fp8_e4m3 q(x);
    return (unsigned char)q.__x;
#endif
}

// LDS-only barrier: wait LDS ops + raw s_barrier — NO vmcnt drain.
// (__syncthreads emits s_waitcnt vmcnt(0), draining in-flight global
// prefetch loads / hist stores every step — the R13 stall.)
__device__ __forceinline__ void ldsbar() {
    asm volatile("s_waitcnt lgkmcnt(0)" ::: "memory");
    __builtin_amdgcn_sched_barrier(0);
    __builtin_amdgcn_s_barrier();
    __builtin_amdgcn_sched_barrier(0);
}

// ---------------------------------------------------------------------------
// K0a: fp8 MFMA B-fragment image of Wh, scaled by 8.
// Slot: [dir][w 8][gg 8][ks 8][lane 64] x 8 bytes:
//   n = (gg>>1)*256 + w*32 + (gg&1)*16 + (lane&15), k = ks*32 + (lane>>4)*8 + e
// ---------------------------------------------------------------------------
__global__ __launch_bounds__(256)
void whimg_kernel(const float* __restrict__ WhF, const float* __restrict__ WhB,
                  unsigned long long* __restrict__ WhT8) {
    const int slot = blockIdx.x * 256 + threadIdx.x;   // 0..65535
    const int dir = slot >> 15, r = slot & 32767;
    const int lane = r & 63;
    const int ks = (r >> 6) & 7;
    const int gg = (r >> 9) & 7;
    const int w  = (r >> 12) & 7;
    const int n = (gg >> 1) * 256 + w * 32 + (gg & 1) * 16 + (lane & 15);
    const int k = ks * 32 + (lane >> 4) * 8;
    const float* src = (dir ? WhB : WhF) + (size_t)n * HSZ + k;
    unsigned long long v = 0;
#pragma unroll
    for (int e = 0; e < 8; ++e)
        v |= (unsigned long long)to_fp8(8.0f * src[e]) << (8 * e);
    WhT8[slot] = v;
}

// ---------------------------------------------------------------------------
// K0b: f16 MFMA B-fragment image of Wi (unscaled).
// ---------------------------------------------------------------------------
__global__ __launch_bounds__(256)
void wiimg_kernel(const float* __restrict__ WiF, const float* __restrict__ WiB,
                  half8* __restrict__ WiT) {
    const int slot = blockIdx.x * 256 + threadIdx.x;   // 0..65535
    const int lane = slot & 63;
    const int ks = (slot >> 6) & 7;
    const int nt = (slot >> 9) & 63;
    const int dir = slot >> 15;
    const int n = nt * 16 + (lane & 15);
    const int k = ks * 32 + (lane >> 4) * 8;
    const float* src = (dir ? WiB : WiF) + (size_t)n * EMB + k;
    half8 hv;
#pragma unroll
    for (int e = 0; e < 8; ++e) hv[e] = (_Float16)src[e];
    WiT[slot] = hv;
}

// ---------------------------------------------------------------------------
// K1: MFMA input GEMM. xWT[dir][bg 16][t][n 1024][4 b] = 64*(embed.Wi + bias)
// grid (512 t, 2 dir), block 256 (4 waves).
// ---------------------------------------------------------------------------
__global__ __launch_bounds__(256, 2)
void gemm_xwt_kernel(const int* __restrict__ X, const float* __restrict__ embed,
                     const half8* __restrict__ WiT, const float* __restrict__ bF,
                     const float* __restrict__ bB, __half* __restrict__ xWT) {
    const int t   = blockIdx.x;
    const int dir = blockIdx.y;
    const int tid = threadIdx.x;
    const int lane = tid & 63;
    const int w    = tid >> 6;
    const int l15  = lane & 15;
    const int lp   = lane >> 4;
    const float* bias = dir ? bB : bF;

    __shared__ ushort A[4 * 8 * 64 * 8];   // [mt][ks][lane][8e] f16 = 32 KB

    {
        const int b = tid >> 2, part = tid & 3;
        const int erow = X[b * TLEN + t];
        const float* src = embed + (size_t)erow * EMB + part * 64;
        const int mt = b >> 4, bl = b & 15;
#pragma unroll
        for (int q = 0; q < 2; ++q) {
            const int ks = part * 2 + q;
#pragma unroll
            for (int lpp = 0; lpp < 4; ++lpp) {
                const float4 x0 = *(const float4*)(src + q * 32 + lpp * 8);
                const float4 x1 = *(const float4*)(src + q * 32 + lpp * 8 + 4);
                half8 hv;
                hv[0]=(_Float16)x0.x; hv[1]=(_Float16)x0.y; hv[2]=(_Float16)x0.z; hv[3]=(_Float16)x0.w;
                hv[4]=(_Float16)x1.x; hv[5]=(_Float16)x1.y; hv[6]=(_Float16)x1.z; hv[7]=(_Float16)x1.w;
                *(half8*)&A[(((mt * 8 + ks) * 64) + lpp * 16 + bl) * 8] = hv;
            }
        }
    }
    __syncthreads();

    half8 afr[4][8];
#pragma unroll
    for (int mt = 0; mt < 4; ++mt)
#pragma unroll
        for (int ks = 0; ks < 8; ++ks)
            afr[mt][ks] = *(const half8*)&A[(((mt * 8 + ks) * 64) + lane) * 8];

    const half8* Bw = WiT + (size_t)(dir * 64 + w * 16) * 8 * 64;

    half8 bcur[8], bnxt[8];
#pragma unroll
    for (int ks = 0; ks < 8; ++ks) bcur[ks] = Bw[(size_t)ks * 64 + lane];

#pragma unroll
    for (int j = 0; j < 16; ++j) {
        if (j < 15) {
#pragma unroll
            for (int ks = 0; ks < 8; ++ks)
                bnxt[ks] = Bw[((size_t)(j + 1) * 8 + ks) * 64 + lane];
        }
        f32x4 acc4[4] = {};
#pragma unroll
        for (int ks = 0; ks < 8; ++ks)
#pragma unroll
            for (int mt = 0; mt < 4; ++mt)
                acc4[mt] = __builtin_amdgcn_mfma_f32_16x16x32_f16(afr[mt][ks], bcur[ks], acc4[mt], 0, 0, 0);

        const int nt = w * 16 + j;
        const float bs = bias[nt * 16 + l15];
#pragma unroll
        for (int mt = 0; mt < 4; ++mt) {
#pragma unroll
            for (int rr = 0; rr < 4; ++rr) {
                const int b = mt * 16 + lp * 4 + rr;
                const __half hh = __float2half(64.0f * (acc4[mt][rr] + bs));
                const int bgD = b >> 2, bo = b & 3;
                xWT[((size_t)((dir * 16 + bgD) * TLEN + t)) * (G4H * 4)
                    + (size_t)(nt * 16 + l15) * 4 + bo] = hh;
            }
        }
#pragma unroll
        for (int ks = 0; ks < 8; ++ks) bcur[ks] = bnxt[ks];
    }
}

// ---------------------------------------------------------------------------
// K2: batch-split LSTM v3b — 4 batches/block, 32 blocks (16 bg x 2 dir).
// Wh fp8 in hard-coded AGPRs a0..a127; full-lane cell update via gbuf.
// Delta vs R13: in-loop barriers are LDS-only (no vmcnt drain) so the xW
// HBM prefetch and hist stores are never drained mid-loop — their latency
// hides across the step. block 512 (8 waves -> 2/SIMD).
// ---------------------------------------------------------------------------

#define WBF1(SLOT, A0, A1)                                                   \
    {                                                                        \
        unsigned long long v_ = base[(SLOT) * 64 + lane];                    \
        unsigned lo_ = (unsigned)v_, hi_ = (unsigned)(v_ >> 32);             \
        asm volatile("v_accvgpr_write_b32 a" A0 ", %0\n\t"                   \
                     "v_accvgpr_write_b32 a" A1 ", %1"                       \
                     :: "v"(lo_), "v"(hi_) : "a" A0, "a" A1);                \
    }

#define MFMA1(ACC, A0, A1)                                                   \
    asm("v_mfma_f32_16x16x32_fp8_fp8 %0, %1, a[" A0 ":" A1 "], %0"           \
        : "+v"(ACC) : "v"(areg))

__global__ __launch_bounds__(512, 2)
void lstm_kernel(const __half* __restrict__ xWT,
                 const unsigned long long* __restrict__ WhT8,
                 __half* __restrict__ hist) {
    const int bg  = blockIdx.x;       // 0..15 (4 batches each)
    const int dir = blockIdx.y;       // 0..1
    const int tid = threadIdx.x;
    const int lane = tid & 63;
    const int w    = tid >> 6;        // wave 0..7
    const int l15  = lane & 15;
    const int lp   = lane >> 4;

    __shared__ unsigned char h8[4096];       // fp8(8*h): [b16][u256] XOR-swz; rows 4..15 stay 0
    __shared__ float gbuf[4 * 4 * 256];      // [b4][gate4][u256] f32 = 16 KB
    __shared__ ushort hstage[4 * 256];       // f16 h: [b4][u256] = 2 KB

    const __half* xwD = xWT + (size_t)(dir * 16 + bg) * ((size_t)TLEN * G4H * 4);
    __half* hD = hist + (size_t)(dir * BATCH + bg * 4) * TLEN * HSZ;

    // ---- load 64 Wh fp8 B-frags into a0..a127 (slot s -> a[2s:2s+1]) ----
    {
        const unsigned long long* base = WhT8 + (size_t)(dir * 8 + w) * 4096;
        WBF1( 0,  "0",  "1") WBF1( 1,  "2",  "3") WBF1( 2,  "4",  "5") WBF1( 3,  "6",  "7")
        WBF1( 4,  "8",  "9") WBF1( 5, "10", "11") WBF1( 6, "12", "13") WBF1( 7, "14", "15")
        WBF1( 8, "16", "17") WBF1( 9, "18", "19") WBF1(10, "20", "21") WBF1(11, "22", "23")
        WBF1(12, "24", "25") WBF1(13, "26", "27") WBF1(14, "28", "29") WBF1(15, "30", "31")
        WBF1(16, "32", "33") WBF1(17, "34", "35") WBF1(18, "36", "37") WBF1(19, "38", "39")
        WBF1(20, "40", "41") WBF1(21, "42", "43") WBF1(22, "44", "45") WBF1(23, "46", "47")
        WBF1(24, "48", "49") WBF1(25, "50", "51") WBF1(26, "52", "53") WBF1(27, "54", "55")
        WBF1(28, "56", "57") WBF1(29, "58", "59") WBF1(30, "60", "61") WBF1(31, "62", "63")
        WBF1(32, "64", "65") WBF1(33, "66", "67") WBF1(34, "68", "69") WBF1(35, "70", "71")
        WBF1(36, "72", "73") WBF1(37, "74", "75") WBF1(38, "76", "77") WBF1(39, "78", "79")
        WBF1(40, "80", "81") WBF1(41, "82", "83") WBF1(42, "84", "85") WBF1(43, "86", "87")
        WBF1(44, "88", "89") WBF1(45, "90", "91") WBF1(46, "92", "93") WBF1(47, "94", "95")
        WBF1(48, "96", "97") WBF1(49, "98", "99") WBF1(50, "100", "101") WBF1(51, "102", "103")
        WBF1(52, "104", "105") WBF1(53, "106", "107") WBF1(54, "108", "109") WBF1(55, "110", "111")
        WBF1(56, "112", "113") WBF1(57, "114", "115") WBF1(58, "116", "117") WBF1(59, "118", "119")
        WBF1(60, "120", "121") WBF1(61, "122", "123") WBF1(62, "124", "125") WBF1(63, "126", "127")
        asm volatile("s_nop 7\n\ts_nop 7" :::);
    }

    for (int i = tid; i < 1024; i += 512) ((unsigned int*)h8)[i] = 0;

    float c0 = 0.0f, c1 = 0.0f;   // cell state for (b=tid>>8, u=tid&255) and (b+2, u)

    const int swzA = (l15 & 7) << 4;
    int xoff[8];
#pragma unroll
    for (int gg = 0; gg < 8; ++gg)
        xoff[gg] = ((gg >> 1) * 256 + w * 32 + (gg & 1) * 16 + l15) * 4;

    f32x4 acc[8];
    u32x2 xwc[8], xwn[8];
    {
        const __half* p0 = xwD + (size_t)(dir ? (TLEN - 1) : 0) * (G4H * 4);
#pragma unroll
        for (int gg = 0; gg < 8; ++gg)
            xwc[gg] = *(const u32x2*)(p0 + xoff[gg]);
    }
    __syncthreads();   // one-time full barrier: h8 init + AGPR loads complete

    for (int ts = 0; ts < TLEN; ++ts) {
        const int t = dir ? (TLEN - 1 - ts) : ts;

        // acc <- 64*xW(t): u32x2 = 4 f16 for batches 0..3 (valid rows lp==0)
#pragma unroll
        for (int gg = 0; gg < 8; ++gg) {
            const half2v lo = __builtin_bit_cast(half2v, xwc[gg][0]);
            const half2v hi = __builtin_bit_cast(half2v, xwc[gg][1]);
            f32x4 a; a[0]=(float)lo[0]; a[1]=(float)lo[1]; a[2]=(float)hi[0]; a[3]=(float)hi[1];
            acc[gg] = a;
        }

        // recurrent matmul: h8 (LDS, rows 0-3 live) x a0..a127 (AGPR) -> acc
#define KS_BLOCK(KS, P0,P1, P2,P3, P4,P5, P6,P7, P8,P9, P10,P11, P12,P13, P14,P15) \
        {                                                                          \
            const unsigned long long areg = *(const unsigned long long*)           \
                (h8 + ((l15 * 256 + (KS) * 32 + lp * 8) ^ swzA));                  \
            MFMA1(acc[0], P0, P1);   MFMA1(acc[1], P2, P3);                        \
            MFMA1(acc[2], P4, P5);   MFMA1(acc[3], P6, P7);                        \
            MFMA1(acc[4], P8, P9);   MFMA1(acc[5], P10, P11);                      \
            MFMA1(acc[6], P12, P13); MFMA1(acc[7], P14, P15);                      \
        }
        KS_BLOCK(0,  "0","1",  "16","17", "32","33", "48","49", "64","65", "80","81", "96","97",  "112","113")
        KS_BLOCK(1,  "2","3",  "18","19", "34","35", "50","51", "66","67", "82","83", "98","99",  "114","115")
        KS_BLOCK(2,  "4","5",  "20","21", "36","37", "52","53", "68","69", "84","85", "100","101","116","117")
        KS_BLOCK(3,  "6","7",  "22","23", "38","39", "54","55", "70","71", "86","87", "102","103","118","119")
        KS_BLOCK(4,  "8","9",  "24","25", "40","41", "56","57", "72","73", "88","89", "104","105","120","121")
        KS_BLOCK(5, "10","11", "26","27", "42","43", "58","59", "74","75", "90","91", "106","107","122","123")
        KS_BLOCK(6, "12","13", "28","29", "44","45", "60","61", "76","77", "92","93", "108","109","124","125")
        KS_BLOCK(7, "14","15", "30","31", "46","47", "62","63", "78","79", "94","95", "110","111","126","127")
#undef KS_BLOCK

        // prefetch next step's xW — never drained by the LDS-only barriers;
        // waited only at next step's unpack (full step of latency cover)
        {
            const int tn = dir ? (t > 0 ? t - 1 : 0) : (t < TLEN - 1 ? t + 1 : t);
            const __half* pp = xwD + (size_t)tn * (G4H * 4);
#pragma unroll
            for (int gg = 0; gg < 8; ++gg)
                xwn[gg] = *(const u32x2*)(pp + xoff[gg]);
        }

        // scatter valid gate values (rows 0-3 live in lp==0 lanes) to gbuf
        if (lp == 0) {
            const int ubase = w * 32 + l15;   // + (gg&1)*16
#pragma unroll
            for (int gg = 0; gg < 8; ++gg) {
                const int g = gg >> 1;
                const int u = ubase + (gg & 1) * 16;
#pragma unroll
                for (int rr = 0; rr < 4; ++rr)
                    gbuf[(rr * 4 + g) * 256 + u] = acc[gg][rr];
            }
        }
        ldsbar();   // B1: gbuf ready (LDS-only wait, no vmcnt drain)

        // full-lane cell update: 1024 (b,u) pairs over 512 threads (2 each)
        {
            const int u = tid & 255, b0 = tid >> 8;   // b0 in {0,1}; also b0+2
            const float sc = 0.015625f;               // 1/64 descale
#pragma unroll
            for (int half = 0; half < 2; ++half) {
                const int b = b0 + half * 2;
                float& cc = half ? c1 : c0;
                const float gi = gbuf[(b * 4 + 0) * 256 + u];
                const float gf = gbuf[(b * 4 + 1) * 256 + u];
                const float gg_ = gbuf[(b * 4 + 2) * 256 + u];
                const float go = gbuf[(b * 4 + 3) * 256 + u];
                const float ig = sigmoid_f(gi * sc);
                const float fg = sigmoid_f(gf * sc);
                const float gv = tanh_f(gg_ * sc);
                const float og = sigmoid_f(go * sc);
                cc = fg * cc + ig * gv;
                const float hv = og * tanh_f(cc);
                const int sw = (b & 7) << 4;
                hstage[b * 256 + u] = __half_as_ushort(__float2half(hv));
                h8[(b * 256 + u) ^ sw] = to_fp8(8.0f * hv);
            }
        }
        ldsbar();   // B2: h(t) complete (LDS-only wait)

        // spill h(t) f16 -> hist (global store, drained only at kernel end)
        {
            const int bl = tid >> 7, us = tid & 127;
            const unsigned v = *(const unsigned*)&hstage[bl * 256 + us * 2];
            *(unsigned*)(hD + ((size_t)bl * TLEN + t) * HSZ + us * 2) = v;
        }

#pragma unroll
        for (int gg = 0; gg < 8; ++gg) xwc[gg] = xwn[gg];
    }
}
#undef WBF1
#undef MFMA1

// ---------------------------------------------------------------------------
// K3: emissions em[b][t][k] = hf(b,t,:).fcW[k,0:256] + hb(b,t,:).fcW[k,256:512]
// ---------------------------------------------------------------------------
__global__ __launch_bounds__(256)
void em_kernel(const __half* __restrict__ hist, const float* __restrict__ fcW,
               float* __restrict__ em) {
    const int b   = blockIdx.x >> 3;
    const int t0  = (blockIdx.x & 7) * 64;
    const int tid = threadIdx.x;

    __shared__ ushort hf[64][264];
    __shared__ ushort hb[64][264];
    __shared__ ushort fcs[32][520];

    for (int i = tid; i < 32 * 512; i += 256) {
        const int k = i >> 9, j = i & 511;
        fcs[k][j] = __half_as_ushort(__float2half(fcW[(size_t)k * HID + j]));
    }
    const __half* hfp = hist;
    const __half* hbp = hist + (size_t)BATCH * TLEN * HSZ;
    for (int i = tid; i < 64 * 32; i += 256) {
        const int row = i >> 5, seg = i & 31;
        const uint4 vf = *(const uint4*)(hfp + ((size_t)b * TLEN + t0 + row) * HSZ + seg*8);
        const uint4 vb = *(const uint4*)(hbp + ((size_t)b * TLEN + t0 + row) * HSZ + seg*8);
        *(uint4*)&hf[row][seg*8] = vf;
        *(uint4*)&hb[row][seg*8] = vb;
    }
    __syncthreads();

    const int tok = tid >> 2;     // 0..63
    const int kq  = tid & 3;      // k = kq*8 + kk
    float s[8] = {0,0,0,0,0,0,0,0};
    for (int j2 = 0; j2 < 128; ++j2) {
        const unsigned hfv = *(const unsigned*)&hf[tok][j2*2];
        const unsigned hbv = *(const unsigned*)&hb[tok][j2*2];
#pragma unroll
        for (int kk = 0; kk < 8; ++kk) {
            const int k = kq*8 + kk;
            s[kk] = fdot2f(hfv, *(const unsigned*)&fcs[k][j2*2], s[kk]);
            s[kk] = fdot2f(hbv, *(const unsigned*)&fcs[k][256 + j2*2], s[kk]);
        }
    }
    float* dst = em + ((size_t)b * TLEN + t0 + tok) * TAGS + kq*8;
#pragma unroll
    for (int kk = 0; kk < 8; ++kk) dst[kk] = s[kk];
}

// ---------------------------------------------------------------------------
// K4: CRF forward + gold score per batch row. grid 64, block 64.
// ---------------------------------------------------------------------------
__global__ void crf_kernel(const float* __restrict__ em, const float* __restrict__ fcb,
                           const float* __restrict__ trans, const float* __restrict__ startv,
                           const float* __restrict__ endv, const int* __restrict__ y,
                           float* __restrict__ partial) {
    const int b   = blockIdx.x;
    const int tid = threadIdx.x;

    __shared__ float alpha_s[TAGS];
    __shared__ float trans_s[TAGS][TAGS + 1];

    for (int i = tid; i < TAGS * TAGS; i += 64)
        trans_s[i >> 5][i & 31] = trans[i];

    const float* e = em + (size_t)b * TLEN * TAGS;

    if (tid < TAGS)
        alpha_s[tid] = startv[tid] + e[tid] + fcb[tid];
    __syncthreads();

    for (int t = 1; t < TLEN; ++t) {
        float anew = 0.0f;
        if (tid < TAGS) {
            float mx = -3.0e38f;
#pragma unroll
            for (int k2 = 0; k2 < TAGS; ++k2)
                mx = fmaxf(mx, alpha_s[k2] + trans_s[k2][tid]);
            float sm = 0.0f;
#pragma unroll
            for (int k2 = 0; k2 < TAGS; ++k2)
                sm += __expf(alpha_s[k2] + trans_s[k2][tid] - mx);
            anew = mx + __logf(sm) + e[t * TAGS + tid] + fcb[tid];
        }
        __syncthreads();
        if (tid < TAGS) alpha_s[tid] = anew;
        __syncthreads();
    }

    float v = (tid < TAGS) ? (alpha_s[tid] + endv[tid]) : -1.0e30f;
    float mx = v;
#pragma unroll
    for (int off = 32; off; off >>= 1) mx = fmaxf(mx, __shfl_xor(mx, off, 64));
    float ex = __expf(v - mx);
#pragma unroll
    for (int off = 32; off; off >>= 1) ex += __shfl_xor(ex, off, 64);
    const float logZ = mx + __logf(ex);

    const int* yb = y + (size_t)b * TLEN;
    float gsum = 0.0f;
    for (int t = tid; t < TLEN; t += 64) {
        const int yt = yb[t];
        gsum += e[t * TAGS + yt] + fcb[yt];
    }
    for (int t = tid; t < TLEN - 1; t += 64)
        gsum += trans[yb[t] * TAGS + yb[t + 1]];
#pragma unroll
    for (int off = 32; off; off >>= 1) gsum += __shfl_xor(gsum, off, 64);

    if (tid == 0) {
        const float num = startv[yb[0]] + gsum + endv[yb[TLEN - 1]];
        partial[b] = logZ - num;
    }
}

// ---------------------------------------------------------------------------
// K5: final mean
// ---------------------------------------------------------------------------
__global__ void reduce_kernel(const float* __restrict__ partial, float* __restrict__ out) {
    float v = partial[threadIdx.x];
#pragma unroll
    for (int off = 32; off; off >>= 1) v += __shfl_xor(v, off, 64);
    if (threadIdx.x == 0) out[0] = v * (1.0f / BATCH);
}

// ---------------------------------------------------------------------------
extern "C" void kernel_launch(void* const* d_in, const int* in_sizes, int n_in,
                              void* d_out, int out_size, void* d_ws, size_t ws_size,
                              hipStream_t stream) {
    (void)in_sizes; (void)n_in; (void)out_size; (void)ws_size;

    const int*   X      = (const int*)  d_in[0];
    const int*   y      = (const int*)  d_in[1];
    const float* embed  = (const float*)d_in[2];
    const float* Wi_f   = (const float*)d_in[3];
    const float* Wh_f   = (const float*)d_in[4];
    const float* b_f    = (const float*)d_in[5];
    const float* Wi_b   = (const float*)d_in[6];
    const float* Wh_b   = (const float*)d_in[7];
    const float* b_b    = (const float*)d_in[8];
    const float* fcW    = (const float*)d_in[9];
    const float* fcb    = (const float*)d_in[10];
    const float* trans  = (const float*)d_in[11];
    const float* startv = (const float*)d_in[12];
    const float* endv   = (const float*)d_in[13];
    float* out = (float*)d_out;

    // workspace layout (em aliases xWT: xWT is dead once lstm_kernel finishes)
    char* ws = (char*)d_ws;
    __half* xWT  = (__half*)(ws);                        // [2][16][512][1024][4] f16 = 134217728 B
    float*  em   = (float*) (ws);                        // alias: [64][512][32] f32 = 4194304 B
    __half* hist = (__half*)(ws + 134217728);            // [2][64][512][256] f16 = 33554432 B
    unsigned long long* WhT8 = (unsigned long long*)(ws + 167772160);  // fp8 Wh image, 524288 B
    half8*  WiT  = (half8*) (ws + 168296448);            // f16 Wi image, 1048576 B
    float*  prt  = (float*) (ws + 169345024);            // 256 B

    whimg_kernel<<<256, 256, 0, stream>>>(Wh_f, Wh_b, WhT8);
    wiimg_kernel<<<256, 256, 0, stream>>>(Wi_f, Wi_b, WiT);

    dim3 ggrid(TLEN, 2);
    gemm_xwt_kernel<<<ggrid, 256, 0, stream>>>(X, embed, WiT, b_f, b_b, xWT);

    dim3 lgrid(16, 2);
    lstm_kernel<<<lgrid, 512, 0, stream>>>(xWT, WhT8, hist);

    em_kernel<<<BATCH * 8, 256, 0, stream>>>(hist, fcW, em);

    crf_kernel<<<BATCH, 64, 0, stream>>>(em, fcb, trans, startv, endv, y, prt);

    reduce_kernel<<<1, 64, 0, stream>>>(prt, out);
}

// Round 15
// 1269.056 us; speedup vs baseline: 2.1092x; 1.2694x over previous
//
#include <hip/hip_runtime.h>
#include <hip/hip_fp16.h>
#include <hip/hip_fp8.h>
#include <stdint.h>

// Problem constants (NamedEntityRecognitionModel)
#define TAGS  32
#define EMB   256
#define HID   512
#define HSZ   256        // per-direction hidden
#define G4H   1024       // 4*HSZ
#define BATCH 64
#define TLEN  512

typedef _Float16 half8  __attribute__((ext_vector_type(8)));
typedef _Float16 half2v __attribute__((ext_vector_type(2)));
typedef float    f32x4  __attribute__((ext_vector_type(4)));

#if defined(__has_builtin)
#if __has_builtin(__builtin_amdgcn_fdot2)
#define HAVE_FDOT2 1
#endif
#if __has_builtin(__builtin_amdgcn_cvt_pk_fp8_f32)
#define HAVE_CVTFP8 1
#endif
#endif

__device__ __forceinline__ float fdot2f(unsigned a, unsigned b, float c) {
    half2v ha = __builtin_bit_cast(half2v, a);
    half2v hb = __builtin_bit_cast(half2v, b);
#ifdef HAVE_FDOT2
    return __builtin_amdgcn_fdot2(ha, hb, c, false);
#else
    return c + (float)ha[0]*(float)hb[0] + (float)ha[1]*(float)hb[1];
#endif
}
__device__ __forceinline__ float sigmoid_f(float x){ return 1.0f/(1.0f+__expf(-x)); }
__device__ __forceinline__ float tanh_f(float x){ return 1.0f - 2.0f/(__expf(2.0f*x)+1.0f); }

// float -> OCP e4m3fn byte (HW convert when available)
__device__ __forceinline__ unsigned char to_fp8(float x) {
#ifdef HAVE_CVTFP8
    return (unsigned char)(__builtin_amdgcn_cvt_pk_fp8_f32(x, x, 0, false) & 0xff);
#else
    __hip_fp8_e4m3 q(x);
    return (unsigned char)q.__x;
#endif
}

// LDS-only barrier (R14-verified equal to __syncthreads here; keeps global
// prefetch/stores undrained in-loop).
__device__ __forceinline__ void ldsbar() {
    asm volatile("s_waitcnt lgkmcnt(0)" ::: "memory");
    __builtin_amdgcn_sched_barrier(0);
    __builtin_amdgcn_s_barrier();
    __builtin_amdgcn_sched_barrier(0);
}

// ---------------------------------------------------------------------------
// K0a: fp8 MFMA B-fragment image of Wh, scaled by 8.
// Slot: [dir][w 8][gg 8][ks 8][lane 64] x 8 bytes:
//   n = (gg>>1)*256 + w*32 + (gg&1)*16 + (lane&15), k = ks*32 + (lane>>4)*8 + e
// ---------------------------------------------------------------------------
__global__ __launch_bounds__(256)
void whimg_kernel(const float* __restrict__ WhF, const float* __restrict__ WhB,
                  unsigned long long* __restrict__ WhT8) {
    const int slot = blockIdx.x * 256 + threadIdx.x;   // 0..65535
    const int dir = slot >> 15, r = slot & 32767;
    const int lane = r & 63;
    const int ks = (r >> 6) & 7;
    const int gg = (r >> 9) & 7;
    const int w  = (r >> 12) & 7;
    const int n = (gg >> 1) * 256 + w * 32 + (gg & 1) * 16 + (lane & 15);
    const int k = ks * 32 + (lane >> 4) * 8;
    const float* src = (dir ? WhB : WhF) + (size_t)n * HSZ + k;
    unsigned long long v = 0;
#pragma unroll
    for (int e = 0; e < 8; ++e)
        v |= (unsigned long long)to_fp8(8.0f * src[e]) << (8 * e);
    WhT8[slot] = v;
}

// ---------------------------------------------------------------------------
// K0b: f16 MFMA B-fragment image of Wi (unscaled).
// ---------------------------------------------------------------------------
__global__ __launch_bounds__(256)
void wiimg_kernel(const float* __restrict__ WiF, const float* __restrict__ WiB,
                  half8* __restrict__ WiT) {
    const int slot = blockIdx.x * 256 + threadIdx.x;   // 0..65535
    const int lane = slot & 63;
    const int ks = (slot >> 6) & 7;
    const int nt = (slot >> 9) & 63;
    const int dir = slot >> 15;
    const int n = nt * 16 + (lane & 15);
    const int k = ks * 32 + (lane >> 4) * 8;
    const float* src = (dir ? WiB : WiF) + (size_t)n * EMB + k;
    half8 hv;
#pragma unroll
    for (int e = 0; e < 8; ++e) hv[e] = (_Float16)src[e];
    WiT[slot] = hv;
}

// ---------------------------------------------------------------------------
// K1: MFMA input GEMM. xWT[dir][b 64][t][n 1024] f16 = 64*(embed.Wi + bias)
// grid (512 t, 2 dir), block 256 (4 waves).
// ---------------------------------------------------------------------------
__global__ __launch_bounds__(256, 2)
void gemm_xwt_kernel(const int* __restrict__ X, const float* __restrict__ embed,
                     const half8* __restrict__ WiT, const float* __restrict__ bF,
                     const float* __restrict__ bB, __half* __restrict__ xWT) {
    const int t   = blockIdx.x;
    const int dir = blockIdx.y;
    const int tid = threadIdx.x;
    const int lane = tid & 63;
    const int w    = tid >> 6;
    const int l15  = lane & 15;
    const int lp   = lane >> 4;
    const float* bias = dir ? bB : bF;

    __shared__ ushort A[4 * 8 * 64 * 8];   // [mt][ks][lane][8e] f16 = 32 KB

    {
        const int b = tid >> 2, part = tid & 3;
        const int erow = X[b * TLEN + t];
        const float* src = embed + (size_t)erow * EMB + part * 64;
        const int mt = b >> 4, bl = b & 15;
#pragma unroll
        for (int q = 0; q < 2; ++q) {
            const int ks = part * 2 + q;
#pragma unroll
            for (int lpp = 0; lpp < 4; ++lpp) {
                const float4 x0 = *(const float4*)(src + q * 32 + lpp * 8);
                const float4 x1 = *(const float4*)(src + q * 32 + lpp * 8 + 4);
                half8 hv;
                hv[0]=(_Float16)x0.x; hv[1]=(_Float16)x0.y; hv[2]=(_Float16)x0.z; hv[3]=(_Float16)x0.w;
                hv[4]=(_Float16)x1.x; hv[5]=(_Float16)x1.y; hv[6]=(_Float16)x1.z; hv[7]=(_Float16)x1.w;
                *(half8*)&A[(((mt * 8 + ks) * 64) + lpp * 16 + bl) * 8] = hv;
            }
        }
    }
    __syncthreads();

    half8 afr[4][8];
#pragma unroll
    for (int mt = 0; mt < 4; ++mt)
#pragma unroll
        for (int ks = 0; ks < 8; ++ks)
            afr[mt][ks] = *(const half8*)&A[(((mt * 8 + ks) * 64) + lane) * 8];

    const half8* Bw = WiT + (size_t)(dir * 64 + w * 16) * 8 * 64;

    half8 bcur[8], bnxt[8];
#pragma unroll
    for (int ks = 0; ks < 8; ++ks) bcur[ks] = Bw[(size_t)ks * 64 + lane];

#pragma unroll
    for (int j = 0; j < 16; ++j) {
        if (j < 15) {
#pragma unroll
            for (int ks = 0; ks < 8; ++ks)
                bnxt[ks] = Bw[((size_t)(j + 1) * 8 + ks) * 64 + lane];
        }
        f32x4 acc4[4] = {};
#pragma unroll
        for (int ks = 0; ks < 8; ++ks)
#pragma unroll
            for (int mt = 0; mt < 4; ++mt)
                acc4[mt] = __builtin_amdgcn_mfma_f32_16x16x32_f16(afr[mt][ks], bcur[ks], acc4[mt], 0, 0, 0);

        const int nt = w * 16 + j;
        const float bs = bias[nt * 16 + l15];
        // write: xWT[((dir*64 + b)*TLEN + t)*G4H + n], b = mt*16+lp*4+rr, n = nt*16+l15
#pragma unroll
        for (int mt = 0; mt < 4; ++mt) {
#pragma unroll
            for (int rr = 0; rr < 4; ++rr) {
                const int b = mt * 16 + lp * 4 + rr;
                const __half hh = __float2half(64.0f * (acc4[mt][rr] + bs));
                xWT[((size_t)((dir * BATCH + b) * TLEN + t)) * G4H + nt * 16 + l15] = hh;
            }
        }
#pragma unroll
        for (int ks = 0; ks < 8; ++ks) bcur[ks] = bnxt[ks];
    }
}

// ---------------------------------------------------------------------------
// K2: batch-split LSTM v4 — ONE batch per block, 128 blocks (64 b x 2 dir),
// half the chip. Wh fp8 in hard-coded AGPRs a0..a127. Per-block per-step
// VALU work is 4x smaller than R13; MFMA count unchanged (the floor).
// block 512 (8 waves -> 2/SIMD). 2 LDS-only barriers/step.
// ---------------------------------------------------------------------------

#define WBF1(SLOT, A0, A1)                                                   \
    {                                                                        \
        unsigned long long v_ = base[(SLOT) * 64 + lane];                    \
        unsigned lo_ = (unsigned)v_, hi_ = (unsigned)(v_ >> 32);             \
        asm volatile("v_accvgpr_write_b32 a" A0 ", %0\n\t"                   \
                     "v_accvgpr_write_b32 a" A1 ", %1"                       \
                     :: "v"(lo_), "v"(hi_) : "a" A0, "a" A1);                \
    }

#define MFMA1(ACC, A0, A1)                                                   \
    asm("v_mfma_f32_16x16x32_fp8_fp8 %0, %1, a[" A0 ":" A1 "], %0"           \
        : "+v"(ACC) : "v"(areg))

__global__ __launch_bounds__(512, 2)
void lstm_kernel(const __half* __restrict__ xWT,
                 const unsigned long long* __restrict__ WhT8,
                 __half* __restrict__ hist) {
    const int bg  = blockIdx.x;       // 0..63 (one batch)
    const int dir = blockIdx.y;       // 0..1
    const int tid = threadIdx.x;
    const int lane = tid & 63;
    const int w    = tid >> 6;        // wave 0..7
    const int l15  = lane & 15;
    const int lp   = lane >> 4;

    __shared__ unsigned char h8[4096];   // fp8(8*h): [row16][u256]; only row 0 live
    __shared__ float gbuf[4 * 256];      // [gate4][u256] f32 = 4 KB
    __shared__ ushort hstage[256];       // f16 h(t)

    const __half* xwD = xWT + (size_t)(dir * BATCH + bg) * ((size_t)TLEN * G4H);
    __half* hD = hist + (size_t)(dir * BATCH + bg) * TLEN * HSZ;

    // ---- load 64 Wh fp8 B-frags into a0..a127 (slot s -> a[2s:2s+1]) ----
    {
        const unsigned long long* base = WhT8 + (size_t)(dir * 8 + w) * 4096;
        WBF1( 0,  "0",  "1") WBF1( 1,  "2",  "3") WBF1( 2,  "4",  "5") WBF1( 3,  "6",  "7")
        WBF1( 4,  "8",  "9") WBF1( 5, "10", "11") WBF1( 6, "12", "13") WBF1( 7, "14", "15")
        WBF1( 8, "16", "17") WBF1( 9, "18", "19") WBF1(10, "20", "21") WBF1(11, "22", "23")
        WBF1(12, "24", "25") WBF1(13, "26", "27") WBF1(14, "28", "29") WBF1(15, "30", "31")
        WBF1(16, "32", "33") WBF1(17, "34", "35") WBF1(18, "36", "37") WBF1(19, "38", "39")
        WBF1(20, "40", "41") WBF1(21, "42", "43") WBF1(22, "44", "45") WBF1(23, "46", "47")
        WBF1(24, "48", "49") WBF1(25, "50", "51") WBF1(26, "52", "53") WBF1(27, "54", "55")
        WBF1(28, "56", "57") WBF1(29, "58", "59") WBF1(30, "60", "61") WBF1(31, "62", "63")
        WBF1(32, "64", "65") WBF1(33, "66", "67") WBF1(34, "68", "69") WBF1(35, "70", "71")
        WBF1(36, "72", "73") WBF1(37, "74", "75") WBF1(38, "76", "77") WBF1(39, "78", "79")
        WBF1(40, "80", "81") WBF1(41, "82", "83") WBF1(42, "84", "85") WBF1(43, "86", "87")
        WBF1(44, "88", "89") WBF1(45, "90", "91") WBF1(46, "92", "93") WBF1(47, "94", "95")
        WBF1(48, "96", "97") WBF1(49, "98", "99") WBF1(50, "100", "101") WBF1(51, "102", "103")
        WBF1(52, "104", "105") WBF1(53, "106", "107") WBF1(54, "108", "109") WBF1(55, "110", "111")
        WBF1(56, "112", "113") WBF1(57, "114", "115") WBF1(58, "116", "117") WBF1(59, "118", "119")
        WBF1(60, "120", "121") WBF1(61, "122", "123") WBF1(62, "124", "125") WBF1(63, "126", "127")
        asm volatile("s_nop 7\n\ts_nop 7" :::);
    }

    for (int i = tid; i < 1024; i += 512) ((unsigned int*)h8)[i] = 0;

    float c0 = 0.0f;                  // cell state for unit tid (tid<256)

    const int swzA = (l15 & 7) << 4;
    int xoff[8];                      // gate index n for this lane
#pragma unroll
    for (int gg = 0; gg < 8; ++gg)
        xoff[gg] = (gg >> 1) * 256 + w * 32 + (gg & 1) * 16 + l15;

    f32x4 acc[8];
    ushort xwc[8], xwn[8];
    {
        const __half* p0 = xwD + (size_t)(dir ? (TLEN - 1) : 0) * G4H;
#pragma unroll
        for (int gg = 0; gg < 8; ++gg)
            xwc[gg] = __half_as_ushort(p0[xoff[gg]]);
    }
    __syncthreads();   // h8 init + AGPR loads complete

    for (int ts = 0; ts < TLEN; ++ts) {
        const int t = dir ? (TLEN - 1 - ts) : ts;

        // acc[gg][0] <- 64*xW(t); rows 1..3 unused (A rows 1..15 are zero)
#pragma unroll
        for (int gg = 0; gg < 8; ++gg) {
            f32x4 a;
            a[0] = (float)__ushort_as_half(xwc[gg]);
            a[1] = 0.0f; a[2] = 0.0f; a[3] = 0.0f;
            acc[gg] = a;
        }

        // recurrent matmul: h8 (row 0 live) x a0..a127 (AGPR) -> acc
#define KS_BLOCK(KS, P0,P1, P2,P3, P4,P5, P6,P7, P8,P9, P10,P11, P12,P13, P14,P15) \
        {                                                                          \
            const unsigned long long areg = *(const unsigned long long*)           \
                (h8 + ((l15 * 256 + (KS) * 32 + lp * 8) ^ swzA));                  \
            MFMA1(acc[0], P0, P1);   MFMA1(acc[1], P2, P3);                        \
            MFMA1(acc[2], P4, P5);   MFMA1(acc[3], P6, P7);                        \
            MFMA1(acc[4], P8, P9);   MFMA1(acc[5], P10, P11);                      \
            MFMA1(acc[6], P12, P13); MFMA1(acc[7], P14, P15);                      \
        }
        KS_BLOCK(0,  "0","1",  "16","17", "32","33", "48","49", "64","65", "80","81", "96","97",  "112","113")
        KS_BLOCK(1,  "2","3",  "18","19", "34","35", "50","51", "66","67", "82","83", "98","99",  "114","115")
        KS_BLOCK(2,  "4","5",  "20","21", "36","37", "52","53", "68","69", "84","85", "100","101","116","117")
        KS_BLOCK(3,  "6","7",  "22","23", "38","39", "54","55", "70","71", "86","87", "102","103","118","119")
        KS_BLOCK(4,  "8","9",  "24","25", "40","41", "56","57", "72","73", "88","89", "104","105","120","121")
        KS_BLOCK(5, "10","11", "26","27", "42","43", "58","59", "74","75", "90","91", "106","107","122","123")
        KS_BLOCK(6, "12","13", "28","29", "44","45", "60","61", "76","77", "92","93", "108","109","124","125")
        KS_BLOCK(7, "14","15", "30","31", "46","47", "62","63", "78","79", "94","95", "110","111","126","127")
#undef KS_BLOCK

        // prefetch next step's xW (8 scalar f16 loads; hides across the step)
        {
            const int tn = dir ? (t > 0 ? t - 1 : 0) : (t < TLEN - 1 ? t + 1 : t);
            const __half* pp = xwD + (size_t)tn * G4H;
#pragma unroll
            for (int gg = 0; gg < 8; ++gg)
                xwn[gg] = __half_as_ushort(pp[xoff[gg]]);
        }

        // scatter valid gate values (row 0 -> lanes lp==0, reg 0) to gbuf
        if (lane < 16) {
            const int ubase = w * 32 + l15;
#pragma unroll
            for (int gg = 0; gg < 8; ++gg)
                gbuf[(gg >> 1) * 256 + ubase + (gg & 1) * 16] = acc[gg][0];
        }
        ldsbar();   // B1: gbuf ready

        // cell update: 256 units over threads 0..255 (waves 4-7 skip)
        if (tid < 256) {
            const int u = tid;
            const float sc = 0.015625f;   // 1/64 descale
            const float ig = sigmoid_f(gbuf[0 * 256 + u] * sc);
            const float fg = sigmoid_f(gbuf[1 * 256 + u] * sc);
            const float gv = tanh_f   (gbuf[2 * 256 + u] * sc);
            const float og = sigmoid_f(gbuf[3 * 256 + u] * sc);
            c0 = fg * c0 + ig * gv;
            const float hv = og * tanh_f(c0);
            hstage[u] = __half_as_ushort(__float2half(hv));
            h8[u] = to_fp8(8.0f * hv);    // row 0: swizzle is identity
        }
        ldsbar();   // B2: h(t) complete

        // spill h(t) f16 -> hist (512 B: threads 0..127 x 4 B)
        if (tid < 128) {
            *(unsigned*)(hD + (size_t)t * HSZ + tid * 2) =
                *(const unsigned*)&hstage[tid * 2];
        }

#pragma unroll
        for (int gg = 0; gg < 8; ++gg) xwc[gg] = xwn[gg];
    }
}
#undef WBF1
#undef MFMA1

// ---------------------------------------------------------------------------
// K3: emissions em[b][t][k] = hf(b,t,:).fcW[k,0:256] + hb(b,t,:).fcW[k,256:512]
// ---------------------------------------------------------------------------
__global__ __launch_bounds__(256)
void em_kernel(const __half* __restrict__ hist, const float* __restrict__ fcW,
               float* __restrict__ em) {
    const int b   = blockIdx.x >> 3;
    const int t0  = (blockIdx.x & 7) * 64;
    const int tid = threadIdx.x;

    __shared__ ushort hf[64][264];
    __shared__ ushort hb[64][264];
    __shared__ ushort fcs[32][520];

    for (int i = tid; i < 32 * 512; i += 256) {
        const int k = i >> 9, j = i & 511;
        fcs[k][j] = __half_as_ushort(__float2half(fcW[(size_t)k * HID + j]));
    }
    const __half* hfp = hist;
    const __half* hbp = hist + (size_t)BATCH * TLEN * HSZ;
    for (int i = tid; i < 64 * 32; i += 256) {
        const int row = i >> 5, seg = i & 31;
        const uint4 vf = *(const uint4*)(hfp + ((size_t)b * TLEN + t0 + row) * HSZ + seg*8);
        const uint4 vb = *(const uint4*)(hbp + ((size_t)b * TLEN + t0 + row) * HSZ + seg*8);
        *(uint4*)&hf[row][seg*8] = vf;
        *(uint4*)&hb[row][seg*8] = vb;
    }
    __syncthreads();

    const int tok = tid >> 2;     // 0..63
    const int kq  = tid & 3;      // k = kq*8 + kk
    float s[8] = {0,0,0,0,0,0,0,0};
    for (int j2 = 0; j2 < 128; ++j2) {
        const unsigned hfv = *(const unsigned*)&hf[tok][j2*2];
        const unsigned hbv = *(const unsigned*)&hb[tok][j2*2];
#pragma unroll
        for (int kk = 0; kk < 8; ++kk) {
            const int k = kq*8 + kk;
            s[kk] = fdot2f(hfv, *(const unsigned*)&fcs[k][j2*2], s[kk]);
            s[kk] = fdot2f(hbv, *(const unsigned*)&fcs[k][256 + j2*2], s[kk]);
        }
    }
    float* dst = em + ((size_t)b * TLEN + t0 + tok) * TAGS + kq*8;
#pragma unroll
    for (int kk = 0; kk < 8; ++kk) dst[kk] = s[kk];
}

// ---------------------------------------------------------------------------
// K4: CRF forward + gold score per batch row. grid 64, block 64.
// ---------------------------------------------------------------------------
__global__ void crf_kernel(const float* __restrict__ em, const float* __restrict__ fcb,
                           const float* __restrict__ trans, const float* __restrict__ startv,
                           const float* __restrict__ endv, const int* __restrict__ y,
                           float* __restrict__ partial) {
    const int b   = blockIdx.x;
    const int tid = threadIdx.x;

    __shared__ float alpha_s[TAGS];
    __shared__ float trans_s[TAGS][TAGS + 1];

    for (int i = tid; i < TAGS * TAGS; i += 64)
        trans_s[i >> 5][i & 31] = trans[i];

    const float* e = em + (size_t)b * TLEN * TAGS;

    if (tid < TAGS)
        alpha_s[tid] = startv[tid] + e[tid] + fcb[tid];
    __syncthreads();

    for (int t = 1; t < TLEN; ++t) {
        float anew = 0.0f;
        if (tid < TAGS) {
            float mx = -3.0e38f;
#pragma unroll
            for (int k2 = 0; k2 < TAGS; ++k2)
                mx = fmaxf(mx, alpha_s[k2] + trans_s[k2][tid]);
            float sm = 0.0f;
#pragma unroll
            for (int k2 = 0; k2 < TAGS; ++k2)
                sm += __expf(alpha_s[k2] + trans_s[k2][tid] - mx);
            anew = mx + __logf(sm) + e[t * TAGS + tid] + fcb[tid];
        }
        __syncthreads();
        if (tid < TAGS) alpha_s[tid] = anew;
        __syncthreads();
    }

    float v = (tid < TAGS) ? (alpha_s[tid] + endv[tid]) : -1.0e30f;
    float mx = v;
#pragma unroll
    for (int off = 32; off; off >>= 1) mx = fmaxf(mx, __shfl_xor(mx, off, 64));
    float ex = __expf(v - mx);
#pragma unroll
    for (int off = 32; off; off >>= 1) ex += __shfl_xor(ex, off, 64);
    const float logZ = mx + __logf(ex);

    const int* yb = y + (size_t)b * TLEN;
    float gsum = 0.0f;
    for (int t = tid; t < TLEN; t += 64) {
        const int yt = yb[t];
        gsum += e[t * TAGS + yt] + fcb[yt];
    }
    for (int t = tid; t < TLEN - 1; t += 64)
        gsum += trans[yb[t] * TAGS + yb[t + 1]];
#pragma unroll
    for (int off = 32; off; off >>= 1) gsum += __shfl_xor(gsum, off, 64);

    if (tid == 0) {
        const float num = startv[yb[0]] + gsum + endv[yb[TLEN - 1]];
        partial[b] = logZ - num;
    }
}

// ---------------------------------------------------------------------------
// K5: final mean
// ---------------------------------------------------------------------------
__global__ void reduce_kernel(const float* __restrict__ partial, float* __restrict__ out) {
    float v = partial[threadIdx.x];
#pragma unroll
    for (int off = 32; off; off >>= 1) v += __shfl_xor(v, off, 64);
    if (threadIdx.x == 0) out[0] = v * (1.0f / BATCH);
}

// ---------------------------------------------------------------------------
extern "C" void kernel_launch(void* const* d_in, const int* in_sizes, int n_in,
                              void* d_out, int out_size, void* d_ws, size_t ws_size,
                              hipStream_t stream) {
    (void)in_sizes; (void)n_in; (void)out_size; (void)ws_size;

    const int*   X      = (const int*)  d_in[0];
    const int*   y      = (const int*)  d_in[1];
    const float* embed  = (const float*)d_in[2];
    const float* Wi_f   = (const float*)d_in[3];
    const float* Wh_f   = (const float*)d_in[4];
    const float* b_f    = (const float*)d_in[5];
    const float* Wi_b   = (const float*)d_in[6];
    const float* Wh_b   = (const float*)d_in[7];
    const float* b_b    = (const float*)d_in[8];
    const float* fcW    = (const float*)d_in[9];
    const float* fcb    = (const float*)d_in[10];
    const float* trans  = (const float*)d_in[11];
    const float* startv = (const float*)d_in[12];
    const float* endv   = (const float*)d_in[13];
    float* out = (float*)d_out;

    // workspace layout (em aliases xWT: xWT is dead once lstm_kernel finishes)
    char* ws = (char*)d_ws;
    __half* xWT  = (__half*)(ws);                        // [2][64][512][1024] f16 = 134217728 B
    float*  em   = (float*) (ws);                        // alias: [64][512][32] f32 = 4194304 B
    __half* hist = (__half*)(ws + 134217728);            // [2][64][512][256] f16 = 33554432 B
    unsigned long long* WhT8 = (unsigned long long*)(ws + 167772160);  // fp8 Wh image, 524288 B
    half8*  WiT  = (half8*) (ws + 168296448);            // f16 Wi image, 1048576 B
    float*  prt  = (float*) (ws + 169345024);            // 256 B

    whimg_kernel<<<256, 256, 0, stream>>>(Wh_f, Wh_b, WhT8);
    wiimg_kernel<<<256, 256, 0, stream>>>(Wi_f, Wi_b, WiT);

    dim3 ggrid(TLEN, 2);
    gemm_xwt_kernel<<<ggrid, 256, 0, stream>>>(X, embed, WiT, b_f, b_b, xWT);

    dim3 lgrid(BATCH, 2);
    lstm_kernel<<<lgrid, 512, 0, stream>>>(xWT, WhT8, hist);

    em_kernel<<<BATCH * 8, 256, 0, stream>>>(hist, fcW, em);

    crf_kernel<<<BATCH, 64, 0, stream>>>(em, fcb, trans, startv, endv, y, prt);

    reduce_kernel<<<1, 64, 0, stream>>>(prt, out);
}